// Round 14
// baseline (14365.009 us; speedup 1.0000x reference)
//
#include <hip/hip_runtime.h>
#include <math.h>

// ---------------------------------------------------------------------------
// MIM RNN round 14: r13 (best, 13.85ms) + A2 merged into A1 -> one 12-job
// conv launch per layer (T,MH + MN,S,X). With ji = blk % 12, each job maps to
// exactly 2 XCDs (3 jobs/XCD ~ 2.5MB < 4MB L2) so weight residency holds.
// Depth-4 A prefetch, XCD-aware decode, split-bf16, XOR-swizzle LDS.
// ---------------------------------------------------------------------------

#define S 524288  // 8*64*1024
typedef unsigned short us;
typedef __attribute__((ext_vector_type(8))) short bf16x8;
typedef __attribute__((ext_vector_type(16))) float f32x16;

__device__ __forceinline__ float sigf(float x) { return 1.0f / (1.0f + expf(-x)); }
__device__ __forceinline__ us f2bf(float f) {
  unsigned u = __float_as_uint(f);
  u += 0x7fffu + ((u >> 16) & 1u);
  return (us)(u >> 16);
}
__device__ __forceinline__ float bf2f(us h) {
  return __uint_as_float(((unsigned)h) << 16);
}
#define MFMA __builtin_amdgcn_mfma_f32_32x32x16_bf16

struct Job {
  const float* x0; const us* w0; int cin0;
  const float* x1; const us* w1; int cin1;
  int taps; float* out; int outCo; int coBase; int coCnt;
};
struct Batch { Job j[12]; int n; };

// ---------------- weight prepack: W'[half][tap][ks][coB4][lane64][8] --------
__global__ void pack_k(us* dst, const float* src, int srcRow0, int nRows,
                       int dstRow0, int ciBase, int cinSrc, int taps, int KS) {
  int idx = blockIdx.x * 256 + threadIdx.x;
  int total = taps * KS * 4 * 64;
  if (idx >= total) return;
  int l = idx & 63, cb = (idx >> 6) & 3, rest = idx >> 8;
  int ks = rest % KS, tap = rest / KS;
  int co_d = cb * 32 + (l & 31);
  if (co_d < dstRow0 || co_d >= dstRow0 + nRows) return;
  int srcRow = srcRow0 + (co_d - dstRow0);
  size_t AH = (size_t)taps * KS * 2048;
  size_t base = ((size_t)(tap * KS + ks) * 4 + cb) * 512 + (size_t)l * 8;
#pragma unroll
  for (int j = 0; j < 8; ++j) {
    int ci = ciBase + ks * 16 + (l >> 5) * 8 + j;
    float v = src[((size_t)srcRow * cinSrc + ci) * taps + tap];
    us hi = f2bf(v);
    dst[base + j] = hi;
    dst[AH + base + j] = f2bf(v - bf2f(hi));
  }
}

__global__ void tr1_k(const float* __restrict__ src, float* __restrict__ dst,
                      int Cin, int Cout) {
  int idx = blockIdx.x * 256 + threadIdx.x;
  if (idx >= Cout * Cin) return;
  int ci = idx % Cin, co = idx / Cin;
  dst[(size_t)ci * Cout + co] = src[idx];
}

// ---------------------------------------------------------------------------
// Conv: block = 256 thr (4 waves) = 128co x 128px (4 img rows, stages 8).
// Wave (wc,wr): 2 co-tiles x 2 px-rows. Slice (tap,kk): 4 A-frags + 4 B LDS
// reads -> 12 MFMA; A prefetch depth 4. ji = blk % n (XCD-resident weights).
__global__ __launch_bounds__(256, 2) void convmf6_k(Batch bt) {
  int blk = blockIdx.x;
  int ji = blk % bt.n;
  int local = blk / bt.n;
  Job J = bt.j[ji];
  int pxg = local & 7;
  int b = local >> 3;
  int r0 = pxg * 4;
  int tid = threadIdx.x, l = tid & 63, wv = tid >> 6;
  int wc = wv & 1, wr = wv >> 1;
  int lcol = l & 31, lg = l >> 5;

  __shared__ __align__(16) unsigned char lds[2][8][2368];

  f32x16 acc[2][2];
#pragma unroll
  for (int r = 0; r < 2; ++r)
#pragma unroll
    for (int j2 = 0; j2 < 2; ++j2)
#pragma unroll
      for (int q = 0; q < 16; ++q) acc[r][j2][q] = 0.f;

  {  // zero halo cols 0,1,34,35: 2 halves x 8 rows x 4 slots x 4 cols = 256
    int e = tid;
    int hh = e & 1, sl = (e >> 1) & 3;
    int row = (e >> 3) & 7, cx = e >> 6;
    int col = cx < 2 ? cx : 32 + cx;
    float4 z = {0.f, 0.f, 0.f, 0.f};
    *(float4*)&lds[hh][row][col * 64 + sl * 16] = z;
  }

  for (int s = 0; s < 2; ++s) {
    const float* X = s ? J.x1 : J.x0;
    const us* W = s ? J.w1 : J.w0;
    int cin = s ? J.cin1 : J.cin0;
    if (cin == 0) continue;
    int KS = cin >> 4;
    size_t AH = (size_t)J.taps * KS * 2048;
    int nst = (cin + 31) >> 5;
    for (int st = 0; st < nst; ++st) {
      int ciCnt = cin - st * 32;
      if (ciCnt > 32) ciCnt = 32;
      int kls = ciCnt >> 4;      // 1 or 2
      int kshift = kls >> 1;     // 0 or 1
      int NS = J.taps * kls;
      auto aaddr = [&](int u) {
        int tap = u >> kshift, kk = u & (kls - 1);
        return W + (((size_t)tap * KS + st * 2 + kk) * 4 + wc * 2) * 512 +
               (size_t)l * 8;
      };
      // depth-4 A prefetch sets (indices always compile-time constants)
      bf16x8 AH0[4], AH1[4], AL0[4], AL1[4];
      auto loadA0 = [&](int u) {
        const us* wp = aaddr(u);
        AH0[0] = *(const bf16x8*)wp; AH1[0] = *(const bf16x8*)(wp + 512);
        AL0[0] = *(const bf16x8*)(wp + AH); AL1[0] = *(const bf16x8*)(wp + AH + 512);
      };
      auto loadA1 = [&](int u) {
        const us* wp = aaddr(u);
        AH0[1] = *(const bf16x8*)wp; AH1[1] = *(const bf16x8*)(wp + 512);
        AL0[1] = *(const bf16x8*)(wp + AH); AL1[1] = *(const bf16x8*)(wp + AH + 512);
      };
      auto loadA2 = [&](int u) {
        const us* wp = aaddr(u);
        AH0[2] = *(const bf16x8*)wp; AH1[2] = *(const bf16x8*)(wp + 512);
        AL0[2] = *(const bf16x8*)(wp + AH); AL1[2] = *(const bf16x8*)(wp + AH + 512);
      };
      auto loadA3 = [&](int u) {
        const us* wp = aaddr(u);
        AH0[3] = *(const bf16x8*)wp; AH1[3] = *(const bf16x8*)(wp + 512);
        AL0[3] = *(const bf16x8*)(wp + AH); AL1[3] = *(const bf16x8*)(wp + AH + 512);
      };
      loadA0(0);
      if (NS > 1) loadA1(1);
      if (NS > 2) loadA2(2);
      if (NS > 3) loadA3(3);
      __syncthreads();
      // stage 8 rows (r0-2 .. r0+5) of up-to-32 ci, hi+lo halves
      for (int u = tid; u < 1024; u += 256) {
        int cp = u & 15;
        int xq = (u >> 4) & 7;
        int row = u >> 7;  // 0..7
        if (2 * cp < ciCnt) {
          int gy = r0 - 2 + row;
          float4 v0 = {0.f, 0.f, 0.f, 0.f}, v1 = {0.f, 0.f, 0.f, 0.f};
          if ((unsigned)gy < 32u) {
            const float* p0 =
                X + (((size_t)b * cin + st * 32 + 2 * cp) << 10) + gy * 32 + xq * 4;
            v0 = *(const float4*)p0;
            v1 = *(const float4*)(p0 + 1024);
          }
          const float* e0 = (const float*)&v0;
          const float* e1 = (const float*)&v1;
          int slot = cp >> 2, boff = (cp & 3) * 4;
#pragma unroll
          for (int e = 0; e < 4; ++e) {
            int col = xq * 4 + 2 + e;
            int off2 = col * 64 + ((slot ^ ((col >> 1) & 3)) << 4) + boff;
            us h0 = f2bf(e0[e]);
            us h1 = f2bf(e1[e]);
            us lo0 = f2bf(e0[e] - bf2f(h0));
            us lo1 = f2bf(e1[e] - bf2f(h1));
            *(unsigned*)&lds[0][row][off2] = (unsigned)h0 | ((unsigned)h1 << 16);
            *(unsigned*)&lds[1][row][off2] = (unsigned)lo0 | ((unsigned)lo1 << 16);
          }
        }
      }
      __syncthreads();
      auto slice = [&](int u, bf16x8 ah0, bf16x8 ah1, bf16x8 al0, bf16x8 al1) {
        int tap = u >> kshift, kk = u & (kls - 1);
        int dy, dx;
        if (J.taps == 1) { dy = 2; dx = 2; }
        else { dy = tap / 5; dx = tap - dy * 5; }
        int col = lcol + dx, cOff = col * 64, swz = (col >> 1) & 3;
        int phys = (((kk * 2 + lg) ^ swz) << 4);
        bf16x8 bb0 = *(const bf16x8*)&lds[0][wr * 2 + dy][cOff + phys];
        bf16x8 bb1 = *(const bf16x8*)&lds[0][wr * 2 + 1 + dy][cOff + phys];
        acc[0][0] = MFMA(ah0, bb0, acc[0][0], 0, 0, 0);
        acc[1][0] = MFMA(ah1, bb0, acc[1][0], 0, 0, 0);
        acc[0][1] = MFMA(ah0, bb1, acc[0][1], 0, 0, 0);
        acc[1][1] = MFMA(ah1, bb1, acc[1][1], 0, 0, 0);
        acc[0][0] = MFMA(al0, bb0, acc[0][0], 0, 0, 0);
        acc[1][0] = MFMA(al1, bb0, acc[1][0], 0, 0, 0);
        acc[0][1] = MFMA(al0, bb1, acc[0][1], 0, 0, 0);
        acc[1][1] = MFMA(al1, bb1, acc[1][1], 0, 0, 0);
        bb0 = *(const bf16x8*)(&lds[0][wr * 2 + dy][cOff + phys] + 8 * 2368);
        bb1 = *(const bf16x8*)(&lds[0][wr * 2 + 1 + dy][cOff + phys] + 8 * 2368);
        acc[0][0] = MFMA(ah0, bb0, acc[0][0], 0, 0, 0);
        acc[1][0] = MFMA(ah1, bb0, acc[1][0], 0, 0, 0);
        acc[0][1] = MFMA(ah0, bb1, acc[0][1], 0, 0, 0);
        acc[1][1] = MFMA(ah1, bb1, acc[1][1], 0, 0, 0);
      };
      for (int uu = 0; uu < NS; uu += 4) {
        slice(uu, AH0[0], AH1[0], AL0[0], AL1[0]);
        if (uu + 4 < NS) loadA0(uu + 4);
        if (uu + 1 < NS) {
          slice(uu + 1, AH0[1], AH1[1], AL0[1], AL1[1]);
          if (uu + 5 < NS) loadA1(uu + 5);
        }
        if (uu + 2 < NS) {
          slice(uu + 2, AH0[2], AH1[2], AL0[2], AL1[2]);
          if (uu + 6 < NS) loadA2(uu + 6);
        }
        if (uu + 3 < NS) {
          slice(uu + 3, AH0[3], AH1[3], AL0[3], AL1[3]);
          if (uu + 7 < NS) loadA3(uu + 7);
        }
      }
    }
  }
  // store: D col = lane&31 (px), row = (reg&3) + 8*(reg>>2) + 4*(lane>>5)
#pragma unroll
  for (int r = 0; r < 2; ++r) {
#pragma unroll
    for (int j2 = 0; j2 < 2; ++j2) {
      int prow = r0 + wr * 2 + j2;
      float* op = J.out + (((size_t)b * J.outCo) << 10) + prow * 32 + lcol;
#pragma unroll
      for (int q = 0; q < 16; ++q) {
        int coLoc = wc * 64 + r * 32 + 4 * lg + (q & 3) + 8 * (q >> 2);
        if (coLoc < J.coCnt)
          op[(size_t)(J.coBase + coLoc) << 10] = acc[r][j2][q];
      }
    }
  }
}

// ---------------------------------------------------------------------------
__global__ void build_net_k(const float* __restrict__ frames0, float* __restrict__ net,
                            int t) {
  int idx = blockIdx.x * 256 + threadIdx.x;
  int b = idx >> 14, ch = (idx >> 10) & 15, p = idx & 1023;
  int y = p >> 5, x = p & 31, py = ch >> 2, px = ch & 3;
  net[idx] = frames0[((size_t)b * 10 + t) * 16384 + (y * 4 + py) * 128 + (x * 4 + px)];
}

// STH [b][256]: i,f,g,o ; STM [b][192]: i',f',g'
__global__ void st_gate1_k(const float* __restrict__ sth, const float* __restrict__ stm,
                           float* __restrict__ c, float* __restrict__ m) {
  int idx = blockIdx.x * 256 + threadIdx.x;
  int b = idx >> 16, r = idx & 65535;
  const float* hb = sth + (size_t)b * 262144 + r;
  const float* mb = stm + (size_t)b * 196608 + r;
  float cn = sigf(hb[65536] + 1.f) * c[idx] + sigf(hb[0]) * tanhf(hb[131072]);
  float mn = sigf(mb[65536] + 1.f) * m[idx] + sigf(mb[0]) * tanhf(mb[131072]);
  c[idx] = cn;
  m[idx] = mn;
}

// fused: conv1(st_cl over [c,m]) + o-gate + h/diff write. grid 128
__global__ __launch_bounds__(256) void st_gate2c1_k(
    const float* __restrict__ c0, const float* __restrict__ m0,
    const float* __restrict__ wcl, const float* __restrict__ sth,
    const float* __restrict__ oS, float* __restrict__ h, float* __restrict__ diff) {
  int blk = blockIdx.x;
  int coB = blk & 3, pb = (blk >> 2) & 3, b = blk >> 4;
  int tid = threadIdx.x, px = pb * 256 + tid;
  float acc[16];
#pragma unroll
  for (int c = 0; c < 16; ++c) acc[c] = 0.f;
  const float* ib1 = c0 + (size_t)b * 65536 + px;
  const float* ib2 = m0 + (size_t)b * 65536 + px;
  for (int ci = 0; ci < 64; ++ci) {
    float v1 = ib1[ci * 1024], v2 = ib2[ci * 1024];
    const float* w1 = wcl + (size_t)ci * 64 + coB * 16;
    const float* w2 = wcl + (size_t)(64 + ci) * 64 + coB * 16;
#pragma unroll
    for (int c = 0; c < 16; ++c) {
      acc[c] = fmaf(w1[c], v1, acc[c]);
      acc[c] = fmaf(w2[c], v2, acc[c]);
    }
  }
#pragma unroll
  for (int c = 0; c < 16; ++c) {
    int co = coB * 16 + c;
    size_t o = (size_t)co * 1024 + px;
    float sto = sth[(size_t)b * 262144 + 196608 + o];
    float hn = sigf(sto + oS[(size_t)b * 65536 + o]) * tanhf(acc[c]);
    size_t ho = (size_t)b * 65536 + o;
    float old = h[ho];
    h[ho] = hn;
    diff[ho] = hn - old;
  }
}

// MN = A + B, chunks i,g,f,o
__global__ void mimn_gate_k(const float* __restrict__ A, const float* __restrict__ Bq,
                            float* __restrict__ dh, float* __restrict__ dc,
                            const float* __restrict__ ctw, const float* __restrict__ ocw) {
  int idx = blockIdx.x * 256 + threadIdx.x;
  int b = idx >> 16, r = idx & 65535;
  const float* a = A + (size_t)b * 262144 + r;
  const float* q = Bq + (size_t)b * 262144 + r;
  float i_ = a[0] + q[0], g_ = a[65536] + q[65536];
  float f_ = a[131072] + q[131072], o_ = a[196608] + q[196608];
  float c0 = dc[idx];
  float cn = sigf(f_ + c0 * ctw[65536 + r] + 1.f) * c0 +
             sigf(i_ + c0 * ctw[r]) * tanhf(g_);
  float hn = sigf(o_ + cn * ocw[r]) * tanhf(cn);
  dc[idx] = cn;
  dh[idx] = hn;
}

// S:i,g,f,o  T:i,g,o  X:i,g,f,o  QH/QX:i,g,f,o (summed)
__global__ void mb_gate1_k(const float* __restrict__ Sb, const float* __restrict__ Tb,
                           const float* __restrict__ Xb, const float* __restrict__ QH,
                           const float* __restrict__ QX, float* __restrict__ m,
                           float* __restrict__ c, float* __restrict__ cc,
                           const float* __restrict__ ctw, const float* __restrict__ ocw) {
  int idx = blockIdx.x * 256 + threadIdx.x;
  int b = idx >> 16, r = idx & 65535;
  const float* sb = Sb + (size_t)b * 262144 + r;
  const float* tb = Tb + (size_t)b * 196608 + r;
  const float* xb = Xb + (size_t)b * 262144 + r;
  const float* qh = QH + (size_t)b * 262144 + r;
  const float* qx = QX + (size_t)b * 262144 + r;
  float i_s = sb[0], g_s = sb[65536], f_s = sb[131072];
  float i_t = tb[0], g_t = tb[65536];
  float i_x = xb[0], g_x = xb[65536], f_x = xb[131072];
  float m0 = m[idx];
  float nm = sigf(f_x + f_s + 1.f) * m0 + sigf(i_x + i_s) * tanhf(g_x + g_s);
  float q_i = qh[0] + qx[0], q_g = qh[65536] + qx[65536];
  float q_f = qh[131072] + qx[131072], q_o = qh[196608] + qx[196608];
  float cc0 = cc[idx];
  float mims = sigf(q_f + cc0 * ctw[65536 + r] + 1.f) * cc0 +
               sigf(q_i + cc0 * ctw[r]) * tanhf(q_g);
  float h2 = sigf(q_o + mims * ocw[r]) * tanhf(mims);
  float nc = h2 + sigf(i_x + i_t) * tanhf(g_x + g_t);
  m[idx] = nm;
  c[idx] = nc;
  cc[idx] = mims;
}

// fused conv1(mb_last over [cI,m0]) + 3-term output gate. grid 128
__global__ __launch_bounds__(256) void mb_gate2c1_k(
    const float* __restrict__ cI, const float* __restrict__ m0,
    const float* __restrict__ wl, const float* __restrict__ Sb,
    const float* __restrict__ Tb, const float* __restrict__ Xb,
    float* __restrict__ h) {
  int blk = blockIdx.x;
  int coB = blk & 3, pb = (blk >> 2) & 3, b = blk >> 4;
  int tid = threadIdx.x, px = pb * 256 + tid;
  float acc[16];
#pragma unroll
  for (int c = 0; c < 16; ++c) acc[c] = 0.f;
  const float* ib1 = cI + (size_t)b * 65536 + px;
  const float* ib2 = m0 + (size_t)b * 65536 + px;
  for (int ci = 0; ci < 64; ++ci) {
    float v1 = ib1[ci * 1024], v2 = ib2[ci * 1024];
    const float* w1 = wl + (size_t)ci * 64 + coB * 16;
    const float* w2 = wl + (size_t)(64 + ci) * 64 + coB * 16;
#pragma unroll
    for (int c = 0; c < 16; ++c) {
      acc[c] = fmaf(w1[c], v1, acc[c]);
      acc[c] = fmaf(w2[c], v2, acc[c]);
    }
  }
#pragma unroll
  for (int c = 0; c < 16; ++c) {
    int co = coB * 16 + c;
    size_t o = (size_t)co * 1024 + px;
    float osum = Xb[(size_t)b * 262144 + 196608 + o] +
                 Tb[(size_t)b * 196608 + 131072 + o] +
                 Sb[(size_t)b * 262144 + 196608 + o];
    h[(size_t)b * 65536 + o] = sigf(osum) * tanhf(acc[c]);
  }
}

// final conv1 w_last + unpatchify. grid 32
__global__ __launch_bounds__(256) void xgen_k(const float* __restrict__ h3,
                                              const float* __restrict__ wwl,
                                              float* __restrict__ xg,
                                              float* __restrict__ out, int t) {
  int blk = blockIdx.x;
  int pb = blk & 3, b = blk >> 2;
  int tid = threadIdx.x, px = pb * 256 + tid;
  float acc[16];
#pragma unroll
  for (int c = 0; c < 16; ++c) acc[c] = 0.f;
  const float* ib = h3 + (size_t)b * 65536 + px;
  for (int ci = 0; ci < 64; ++ci) {
    float v = ib[ci * 1024];
    const float* w = wwl + (size_t)ci * 16;
#pragma unroll
    for (int c = 0; c < 16; ++c) acc[c] = fmaf(w[c], v, acc[c]);
  }
  int y = px >> 5, x = px & 31;
#pragma unroll
  for (int c = 0; c < 16; ++c) {
    xg[(size_t)b * 16384 + (size_t)c * 1024 + px] = acc[c];
    if (t >= 9) {
      int py = c >> 2, pxs = c & 3;
      out[((size_t)b * 10 + (t - 9)) * 16384 + (y * 4 + py) * 128 + (x * 4 + pxs)] =
          acc[c];
    }
  }
}

// ---------------------------------------------------------------------------
extern "C" void kernel_launch(void* const* d_in, const int* in_sizes, int n_in,
                              void* d_out, int out_size, void* d_ws, size_t ws_size,
                              hipStream_t stream) {
  const float* frames0 = (const float*)d_in[0];
  const float* st_cx = (const float*)d_in[2];
  const float* st_ch = (const float*)d_in[3];
  const float* st_cm = (const float*)d_in[4];
  const float* st_co = (const float*)d_in[5];
  const float* st_cl = (const float*)d_in[6];
  const float* mb_t = (const float*)d_in[7];
  const float* mb_s = (const float*)d_in[8];
  const float* mb_x = (const float*)d_in[9];
  const float* mb_mh = (const float*)d_in[10];
  const float* mb_mx = (const float*)d_in[11];
  const float* mb_ctw = (const float*)d_in[12];
  const float* mb_ocw = (const float*)d_in[13];
  const float* mb_last = (const float*)d_in[14];
  const float* mn_ch = (const float*)d_in[15];
  const float* mn_cx = (const float*)d_in[16];
  const float* mn_ctw = (const float*)d_in[17];
  const float* mn_ocw = (const float*)d_in[18];
  const float* w_last = (const float*)d_in[19];
  float* out = (float*)d_out;

  float* ws = (float*)d_ws;
  size_t off = 0;
  auto A_ = [&](size_t n) { float* p = ws + off; off += n; return p; };
  float* hs[4]; for (int i = 0; i < 4; ++i) hs[i] = A_(S);
  float* cs[4]; for (int i = 0; i < 4; ++i) cs[i] = A_(S);
  float* memb = A_(S);
  float* dh[3]; for (int i = 0; i < 3; ++i) dh[i] = A_(S);
  float* dcb[3]; for (int i = 0; i < 3; ++i) dcb[i] = A_(S);
  float* ccb[3]; for (int i = 0; i < 3; ++i) ccb[i] = A_(S);
  float* diffb = A_(S);
  size_t zeroFloats = off;  // 19*S
  float* xgen = A_(131072);
  float* netb = A_(131072);
  float* R1 = A_(4 * S);   // STH / MNa / QX
  float* RB = A_(4 * S);   // MNb
  float* R2 = A_(3 * S);   // STM / T
  float* R3 = A_(4 * S);   // X
  float* R5 = A_(4 * S);   // Sconv
  float* RM = A_(4 * S);   // MH (QH)
  float* B64a = A_(S);     // STO
  float* wtmbl[3]; for (int li = 0; li < 3; ++li) wtmbl[li] = A_(8192);
  float* wtcl = A_(8192);
  float* wtwl = A_(1024);
  us* warena = (us*)(ws + off);

  size_t wOff = 0;
  auto alloc = [&](int taps, int KS) {
    size_t o = wOff;
    wOff += (size_t)2 * taps * KS * 2048;
    return o;
  };
  size_t oSTH0n = alloc(25, 1), oSTH0h = alloc(25, 4);
  size_t oSTH1n = alloc(25, 1), oSTH1h = alloc(25, 4);
  size_t oSTM0n = alloc(25, 1), oSTM0m = alloc(25, 4);
  size_t oSTM1n = alloc(25, 1), oSTM1m = alloc(25, 4);
  size_t oSTOa = alloc(25, 4), oSTOb = alloc(25, 4);
  size_t oMNa0[3], oMNa1[3], oMNb0[3], oMNb1[3], oS0[3], oS1[3], oT0[3], oT1[3],
      oX0[3], oX1[3], oMH0[3], oMH1[3], oMX0[3], oMX1[3];
  for (int li = 0; li < 3; ++li) {
    oMNa0[li] = alloc(25, 4); oMNa1[li] = alloc(25, 4);
    oMNb0[li] = alloc(25, 4); oMNb1[li] = alloc(25, 4);
    oS0[li] = alloc(25, 4); oS1[li] = alloc(25, 4);
    oT0[li] = alloc(25, 4); oT1[li] = alloc(25, 4);
    oX0[li] = alloc(25, 4); oX1[li] = alloc(25, 4);
    oMH0[li] = alloc(25, 4); oMH1[li] = alloc(25, 4);
    oMX0[li] = alloc(25, 4); oMX1[li] = alloc(25, 4);
  }
  if (ws_size < off * sizeof(float) + wOff * sizeof(us)) return;

  hipMemsetAsync(ws, 0, zeroFloats * sizeof(float), stream);
  hipMemsetAsync(warena, 0, wOff * sizeof(us), stream);

  auto packL = [&](size_t dstOff, const float* src, int srcRow0, int nRows,
                   int dstRow0, int ciBase, int cinSrc, int taps, int KS) {
    int total = taps * KS * 4 * 64;
    pack_k<<<(total + 255) / 256, 256, 0, stream>>>(warena + dstOff, src, srcRow0,
                                                    nRows, dstRow0, ciBase, cinSrc,
                                                    taps, KS);
  };
  // st_cx rows: i(0) f(64) g(128) i'(192) f'(256) g'(320) o(384)
  packL(oSTH0n, st_cx, 0, 128, 0, 0, 16, 25, 1);
  packL(oSTH0h, st_ch, 0, 128, 0, 0, 64, 25, 4);
  packL(oSTH1n, st_cx, 128, 64, 0, 0, 16, 25, 1);
  packL(oSTH1n, st_cx, 384, 64, 64, 0, 16, 25, 1);
  packL(oSTH1h, st_ch, 128, 128, 0, 0, 64, 25, 4);
  packL(oSTM0n, st_cx, 192, 128, 0, 0, 16, 25, 1);
  packL(oSTM0m, st_cm, 0, 128, 0, 0, 64, 25, 4);
  packL(oSTM1n, st_cx, 320, 64, 0, 0, 16, 25, 1);
  packL(oSTM1m, st_cm, 128, 64, 0, 0, 64, 25, 4);
  packL(oSTOa, st_co, 0, 64, 0, 0, 128, 25, 4);
  packL(oSTOb, st_co, 0, 64, 0, 64, 128, 25, 4);
  for (int li = 0; li < 3; ++li) {
    const float* ch = mn_ch + (size_t)li * 409600;
    const float* cx = mn_cx + (size_t)li * 409600;
    const float* mbs = mb_s + (size_t)li * 409600;
    const float* mbt = mb_t + (size_t)li * 307200;
    const float* mbx = mb_x + (size_t)li * 409600;
    const float* mmh = mb_mh + (size_t)li * 409600;
    const float* mmx = mb_mx + (size_t)li * 409600;
    packL(oMNa0[li], ch, 0, 128, 0, 0, 64, 25, 4);
    packL(oMNa1[li], ch, 128, 128, 0, 0, 64, 25, 4);
    packL(oMNb0[li], cx, 0, 128, 0, 0, 64, 25, 4);
    packL(oMNb1[li], cx, 128, 128, 0, 0, 64, 25, 4);
    packL(oS0[li], mbs, 0, 128, 0, 0, 64, 25, 4);
    packL(oS1[li], mbs, 128, 128, 0, 0, 64, 25, 4);
    packL(oT0[li], mbt, 0, 128, 0, 0, 64, 25, 4);
    packL(oT1[li], mbt, 128, 64, 0, 0, 64, 25, 4);
    packL(oX0[li], mbx, 0, 128, 0, 0, 64, 25, 4);
    packL(oX1[li], mbx, 128, 128, 0, 0, 64, 25, 4);
    packL(oMH0[li], mmh, 0, 128, 0, 0, 64, 25, 4);
    packL(oMH1[li], mmh, 128, 128, 0, 0, 64, 25, 4);
    packL(oMX0[li], mmx, 0, 128, 0, 0, 64, 25, 4);
    packL(oMX1[li], mmx, 128, 128, 0, 0, 64, 25, 4);
    tr1_k<<<32, 256, 0, stream>>>(mb_last + (size_t)li * 8192, wtmbl[li], 128, 64);
  }
  tr1_k<<<32, 256, 0, stream>>>(st_cl, wtcl, 128, 64);
  tr1_k<<<4, 256, 0, stream>>>(w_last, wtwl, 64, 16);

  auto mkj = [&](const float* x0, size_t w0, int cin0, const float* x1, size_t w1,
                 int cin1, int taps, float* o, int outCo, int coBase, int coCnt) {
    Job j;
    j.x0 = x0; j.w0 = warena + w0; j.cin0 = cin0;
    j.x1 = x1; j.w1 = warena + w1; j.cin1 = cin1;
    j.taps = taps; j.out = o; j.outCo = outCo; j.coBase = coBase; j.coCnt = coCnt;
    return j;
  };
  auto launchB = [&](Batch& bt) {
    convmf6_k<<<bt.n * 64, 256, 0, stream>>>(bt);
  };

  for (int t = 0; t < 19; ++t) {
    const float* stIn = (t < 10) ? netb : xgen;
    if (t < 10) build_net_k<<<512, 256, 0, stream>>>(frames0, netb, t);
    {  // STH + STM (4 jobs -> XCD pairs)
      Batch P; P.n = 4;
      P.j[0] = mkj(stIn, oSTH0n, 16, hs[0], oSTH0h, 64, 25, R1, 256, 0, 128);
      P.j[1] = mkj(stIn, oSTH1n, 16, hs[0], oSTH1h, 64, 25, R1, 256, 128, 128);
      P.j[2] = mkj(stIn, oSTM0n, 16, memb, oSTM0m, 64, 25, R2, 192, 0, 128);
      P.j[3] = mkj(stIn, oSTM1n, 16, memb, oSTM1m, 64, 25, R2, 192, 128, 64);
      launchB(P);
    }
    st_gate1_k<<<2048, 256, 0, stream>>>(R1, R2, cs[0], memb);
    {  // STO
      Batch P; P.n = 1;
      P.j[0] = mkj(cs[0], oSTOa, 64, memb, oSTOb, 64, 25, B64a, 64, 0, 64);
      launchB(P);
    }
    st_gate2c1_k<<<128, 256, 0, stream>>>(cs[0], memb, wtcl, R1, B64a, hs[0], diffb);

    for (int i = 1; i < 4; ++i) {
      int li = i - 1;
      const float* din = (i == 1) ? diffb : dh[i - 2];
      {  // merged A: T + MH + (MNa,MNb if t>=1) + S + X -> 12 jobs (8 at t=0)
        Batch P; int n = 0;
        P.j[n++] = mkj(hs[i], oT0[li], 64, nullptr, 0, 0, 25, R2, 192, 0, 128);
        P.j[n++] = mkj(hs[i], oT1[li], 64, nullptr, 0, 0, 25, R2, 192, 128, 64);
        P.j[n++] = mkj(cs[i], oMH0[li], 64, nullptr, 0, 0, 25, RM, 256, 0, 128);
        P.j[n++] = mkj(cs[i], oMH1[li], 64, nullptr, 0, 0, 25, RM, 256, 128, 128);
        if (t >= 1) {
          P.j[n++] = mkj(dh[li], oMNa0[li], 64, nullptr, 0, 0, 25, R1, 256, 0, 128);
          P.j[n++] = mkj(dh[li], oMNa1[li], 64, nullptr, 0, 0, 25, R1, 256, 128, 128);
          P.j[n++] = mkj(din, oMNb0[li], 64, nullptr, 0, 0, 25, RB, 256, 0, 128);
          P.j[n++] = mkj(din, oMNb1[li], 64, nullptr, 0, 0, 25, RB, 256, 128, 128);
        }
        P.j[n++] = mkj(memb, oS0[li], 64, nullptr, 0, 0, 25, R5, 256, 0, 128);
        P.j[n++] = mkj(memb, oS1[li], 64, nullptr, 0, 0, 25, R5, 256, 128, 128);
        P.j[n++] = mkj(hs[i - 1], oX0[li], 64, nullptr, 0, 0, 25, R3, 256, 0, 128);
        P.j[n++] = mkj(hs[i - 1], oX1[li], 64, nullptr, 0, 0, 25, R3, 256, 128, 128);
        P.n = n;
        launchB(P);
      }
      if (t >= 1)
        mimn_gate_k<<<2048, 256, 0, stream>>>(R1, RB, dh[li], dcb[li],
                                              mn_ctw + (size_t)li * 131072,
                                              mn_ocw + (size_t)li * 65536);
      {  // MX (dh post-update; zeros at t=0 -> QX = 0, matches reference)
        Batch P; P.n = 2;
        P.j[0] = mkj(dh[li], oMX0[li], 64, nullptr, 0, 0, 25, R1, 256, 0, 128);
        P.j[1] = mkj(dh[li], oMX1[li], 64, nullptr, 0, 0, 25, R1, 256, 128, 128);
        launchB(P);
      }
      mb_gate1_k<<<2048, 256, 0, stream>>>(R5, R2, R3, RM, R1, memb, cs[i], ccb[li],
                                           mb_ctw + (size_t)li * 131072,
                                           mb_ocw + (size_t)li * 65536);
      mb_gate2c1_k<<<128, 256, 0, stream>>>(cs[i], memb, wtmbl[li], R5, R2, R3, hs[i]);
    }
    xgen_k<<<32, 256, 0, stream>>>(hs[3], wtwl, xgen, out, t);
  }
}

// Round 15
// 13404.730 us; speedup vs baseline: 1.0716x; 1.0716x over previous
//
#include <hip/hip_runtime.h>
#include <math.h>

// ---------------------------------------------------------------------------
// MIM RNN round 15: r13 (best, 13.85ms) + all T/MH jobs hoisted into the
// step-leading 16-job batch (1024 blocks = 2.0 machine rounds, XCD-pinned).
// Removes 3 conv launches/step without touching the MN critical path.
// Depth-4 A prefetch, split-bf16, XOR-swizzle LDS.
// ---------------------------------------------------------------------------

#define S 524288  // 8*64*1024
typedef unsigned short us;
typedef __attribute__((ext_vector_type(8))) short bf16x8;
typedef __attribute__((ext_vector_type(16))) float f32x16;

__device__ __forceinline__ float sigf(float x) { return 1.0f / (1.0f + expf(-x)); }
__device__ __forceinline__ us f2bf(float f) {
  unsigned u = __float_as_uint(f);
  u += 0x7fffu + ((u >> 16) & 1u);
  return (us)(u >> 16);
}
__device__ __forceinline__ float bf2f(us h) {
  return __uint_as_float(((unsigned)h) << 16);
}
#define MFMA __builtin_amdgcn_mfma_f32_32x32x16_bf16

struct Job {
  const float* x0; const us* w0; int cin0;
  const float* x1; const us* w1; int cin1;
  int taps; float* out; int outCo; int coBase; int coCnt;
};
struct Batch { Job j[16]; int n; };

// ---------------- weight prepack: W'[half][tap][ks][coB4][lane64][8] --------
__global__ void pack_k(us* dst, const float* src, int srcRow0, int nRows,
                       int dstRow0, int ciBase, int cinSrc, int taps, int KS) {
  int idx = blockIdx.x * 256 + threadIdx.x;
  int total = taps * KS * 4 * 64;
  if (idx >= total) return;
  int l = idx & 63, cb = (idx >> 6) & 3, rest = idx >> 8;
  int ks = rest % KS, tap = rest / KS;
  int co_d = cb * 32 + (l & 31);
  if (co_d < dstRow0 || co_d >= dstRow0 + nRows) return;
  int srcRow = srcRow0 + (co_d - dstRow0);
  size_t AH = (size_t)taps * KS * 2048;
  size_t base = ((size_t)(tap * KS + ks) * 4 + cb) * 512 + (size_t)l * 8;
#pragma unroll
  for (int j = 0; j < 8; ++j) {
    int ci = ciBase + ks * 16 + (l >> 5) * 8 + j;
    float v = src[((size_t)srcRow * cinSrc + ci) * taps + tap];
    us hi = f2bf(v);
    dst[base + j] = hi;
    dst[AH + base + j] = f2bf(v - bf2f(hi));
  }
}

__global__ void tr1_k(const float* __restrict__ src, float* __restrict__ dst,
                      int Cin, int Cout) {
  int idx = blockIdx.x * 256 + threadIdx.x;
  if (idx >= Cout * Cin) return;
  int ci = idx % Cin, co = idx / Cin;
  dst[(size_t)ci * Cout + co] = src[idx];
}

// ---------------------------------------------------------------------------
// Conv: block = 256 thr (4 waves) = 128co x 128px (4 img rows, stages 8).
// Wave (wc,wr): 2 co-tiles x 2 px-rows. Slice (tap,kk): 4 A-frags + 4 B LDS
// reads -> 12 MFMA; A prefetch depth 4. ji = blk % n (XCD-resident weights).
__global__ __launch_bounds__(256, 2) void convmf6_k(Batch bt) {
  int blk = blockIdx.x;
  int ji = blk % bt.n;
  int local = blk / bt.n;
  Job J = bt.j[ji];
  int pxg = local & 7;
  int b = local >> 3;
  int r0 = pxg * 4;
  int tid = threadIdx.x, l = tid & 63, wv = tid >> 6;
  int wc = wv & 1, wr = wv >> 1;
  int lcol = l & 31, lg = l >> 5;

  __shared__ __align__(16) unsigned char lds[2][8][2368];

  f32x16 acc[2][2];
#pragma unroll
  for (int r = 0; r < 2; ++r)
#pragma unroll
    for (int j2 = 0; j2 < 2; ++j2)
#pragma unroll
      for (int q = 0; q < 16; ++q) acc[r][j2][q] = 0.f;

  {  // zero halo cols 0,1,34,35: 2 halves x 8 rows x 4 slots x 4 cols = 256
    int e = tid;
    int hh = e & 1, sl = (e >> 1) & 3;
    int row = (e >> 3) & 7, cx = e >> 6;
    int col = cx < 2 ? cx : 32 + cx;
    float4 z = {0.f, 0.f, 0.f, 0.f};
    *(float4*)&lds[hh][row][col * 64 + sl * 16] = z;
  }

  for (int s = 0; s < 2; ++s) {
    const float* X = s ? J.x1 : J.x0;
    const us* W = s ? J.w1 : J.w0;
    int cin = s ? J.cin1 : J.cin0;
    if (cin == 0) continue;
    int KS = cin >> 4;
    size_t AH = (size_t)J.taps * KS * 2048;
    int nst = (cin + 31) >> 5;
    for (int st = 0; st < nst; ++st) {
      int ciCnt = cin - st * 32;
      if (ciCnt > 32) ciCnt = 32;
      int kls = ciCnt >> 4;      // 1 or 2
      int kshift = kls >> 1;     // 0 or 1
      int NS = J.taps * kls;
      auto aaddr = [&](int u) {
        int tap = u >> kshift, kk = u & (kls - 1);
        return W + (((size_t)tap * KS + st * 2 + kk) * 4 + wc * 2) * 512 +
               (size_t)l * 8;
      };
      // depth-4 A prefetch sets (indices always compile-time constants)
      bf16x8 AH0[4], AH1[4], AL0[4], AL1[4];
      auto loadA0 = [&](int u) {
        const us* wp = aaddr(u);
        AH0[0] = *(const bf16x8*)wp; AH1[0] = *(const bf16x8*)(wp + 512);
        AL0[0] = *(const bf16x8*)(wp + AH); AL1[0] = *(const bf16x8*)(wp + AH + 512);
      };
      auto loadA1 = [&](int u) {
        const us* wp = aaddr(u);
        AH0[1] = *(const bf16x8*)wp; AH1[1] = *(const bf16x8*)(wp + 512);
        AL0[1] = *(const bf16x8*)(wp + AH); AL1[1] = *(const bf16x8*)(wp + AH + 512);
      };
      auto loadA2 = [&](int u) {
        const us* wp = aaddr(u);
        AH0[2] = *(const bf16x8*)wp; AH1[2] = *(const bf16x8*)(wp + 512);
        AL0[2] = *(const bf16x8*)(wp + AH); AL1[2] = *(const bf16x8*)(wp + AH + 512);
      };
      auto loadA3 = [&](int u) {
        const us* wp = aaddr(u);
        AH0[3] = *(const bf16x8*)wp; AH1[3] = *(const bf16x8*)(wp + 512);
        AL0[3] = *(const bf16x8*)(wp + AH); AL1[3] = *(const bf16x8*)(wp + AH + 512);
      };
      loadA0(0);
      if (NS > 1) loadA1(1);
      if (NS > 2) loadA2(2);
      if (NS > 3) loadA3(3);
      __syncthreads();
      // stage 8 rows (r0-2 .. r0+5) of up-to-32 ci, hi+lo halves
      for (int u = tid; u < 1024; u += 256) {
        int cp = u & 15;
        int xq = (u >> 4) & 7;
        int row = u >> 7;  // 0..7
        if (2 * cp < ciCnt) {
          int gy = r0 - 2 + row;
          float4 v0 = {0.f, 0.f, 0.f, 0.f}, v1 = {0.f, 0.f, 0.f, 0.f};
          if ((unsigned)gy < 32u) {
            const float* p0 =
                X + (((size_t)b * cin + st * 32 + 2 * cp) << 10) + gy * 32 + xq * 4;
            v0 = *(const float4*)p0;
            v1 = *(const float4*)(p0 + 1024);
          }
          const float* e0 = (const float*)&v0;
          const float* e1 = (const float*)&v1;
          int slot = cp >> 2, boff = (cp & 3) * 4;
#pragma unroll
          for (int e = 0; e < 4; ++e) {
            int col = xq * 4 + 2 + e;
            int off2 = col * 64 + ((slot ^ ((col >> 1) & 3)) << 4) + boff;
            us h0 = f2bf(e0[e]);
            us h1 = f2bf(e1[e]);
            us lo0 = f2bf(e0[e] - bf2f(h0));
            us lo1 = f2bf(e1[e] - bf2f(h1));
            *(unsigned*)&lds[0][row][off2] = (unsigned)h0 | ((unsigned)h1 << 16);
            *(unsigned*)&lds[1][row][off2] = (unsigned)lo0 | ((unsigned)lo1 << 16);
          }
        }
      }
      __syncthreads();
      auto slice = [&](int u, bf16x8 ah0, bf16x8 ah1, bf16x8 al0, bf16x8 al1) {
        int tap = u >> kshift, kk = u & (kls - 1);
        int dy, dx;
        if (J.taps == 1) { dy = 2; dx = 2; }
        else { dy = tap / 5; dx = tap - dy * 5; }
        int col = lcol + dx, cOff = col * 64, swz = (col >> 1) & 3;
        int phys = (((kk * 2 + lg) ^ swz) << 4);
        bf16x8 bb0 = *(const bf16x8*)&lds[0][wr * 2 + dy][cOff + phys];
        bf16x8 bb1 = *(const bf16x8*)&lds[0][wr * 2 + 1 + dy][cOff + phys];
        acc[0][0] = MFMA(ah0, bb0, acc[0][0], 0, 0, 0);
        acc[1][0] = MFMA(ah1, bb0, acc[1][0], 0, 0, 0);
        acc[0][1] = MFMA(ah0, bb1, acc[0][1], 0, 0, 0);
        acc[1][1] = MFMA(ah1, bb1, acc[1][1], 0, 0, 0);
        acc[0][0] = MFMA(al0, bb0, acc[0][0], 0, 0, 0);
        acc[1][0] = MFMA(al1, bb0, acc[1][0], 0, 0, 0);
        acc[0][1] = MFMA(al0, bb1, acc[0][1], 0, 0, 0);
        acc[1][1] = MFMA(al1, bb1, acc[1][1], 0, 0, 0);
        bb0 = *(const bf16x8*)(&lds[0][wr * 2 + dy][cOff + phys] + 8 * 2368);
        bb1 = *(const bf16x8*)(&lds[0][wr * 2 + 1 + dy][cOff + phys] + 8 * 2368);
        acc[0][0] = MFMA(ah0, bb0, acc[0][0], 0, 0, 0);
        acc[1][0] = MFMA(ah1, bb0, acc[1][0], 0, 0, 0);
        acc[0][1] = MFMA(ah0, bb1, acc[0][1], 0, 0, 0);
        acc[1][1] = MFMA(ah1, bb1, acc[1][1], 0, 0, 0);
      };
      for (int uu = 0; uu < NS; uu += 4) {
        slice(uu, AH0[0], AH1[0], AL0[0], AL1[0]);
        if (uu + 4 < NS) loadA0(uu + 4);
        if (uu + 1 < NS) {
          slice(uu + 1, AH0[1], AH1[1], AL0[1], AL1[1]);
          if (uu + 5 < NS) loadA1(uu + 5);
        }
        if (uu + 2 < NS) {
          slice(uu + 2, AH0[2], AH1[2], AL0[2], AL1[2]);
          if (uu + 6 < NS) loadA2(uu + 6);
        }
        if (uu + 3 < NS) {
          slice(uu + 3, AH0[3], AH1[3], AL0[3], AL1[3]);
          if (uu + 7 < NS) loadA3(uu + 7);
        }
      }
    }
  }
  // store: D col = lane&31 (px), row = (reg&3) + 8*(reg>>2) + 4*(lane>>5)
#pragma unroll
  for (int r = 0; r < 2; ++r) {
#pragma unroll
    for (int j2 = 0; j2 < 2; ++j2) {
      int prow = r0 + wr * 2 + j2;
      float* op = J.out + (((size_t)b * J.outCo) << 10) + prow * 32 + lcol;
#pragma unroll
      for (int q = 0; q < 16; ++q) {
        int coLoc = wc * 64 + r * 32 + 4 * lg + (q & 3) + 8 * (q >> 2);
        if (coLoc < J.coCnt)
          op[(size_t)(J.coBase + coLoc) << 10] = acc[r][j2][q];
      }
    }
  }
}

// ---------------------------------------------------------------------------
__global__ void build_net_k(const float* __restrict__ frames0, float* __restrict__ net,
                            int t) {
  int idx = blockIdx.x * 256 + threadIdx.x;
  int b = idx >> 14, ch = (idx >> 10) & 15, p = idx & 1023;
  int y = p >> 5, x = p & 31, py = ch >> 2, px = ch & 3;
  net[idx] = frames0[((size_t)b * 10 + t) * 16384 + (y * 4 + py) * 128 + (x * 4 + px)];
}

// STH [b][256]: i,f,g,o ; STM [b][192]: i',f',g'
__global__ void st_gate1_k(const float* __restrict__ sth, const float* __restrict__ stm,
                           float* __restrict__ c, float* __restrict__ m) {
  int idx = blockIdx.x * 256 + threadIdx.x;
  int b = idx >> 16, r = idx & 65535;
  const float* hb = sth + (size_t)b * 262144 + r;
  const float* mb = stm + (size_t)b * 196608 + r;
  float cn = sigf(hb[65536] + 1.f) * c[idx] + sigf(hb[0]) * tanhf(hb[131072]);
  float mn = sigf(mb[65536] + 1.f) * m[idx] + sigf(mb[0]) * tanhf(mb[131072]);
  c[idx] = cn;
  m[idx] = mn;
}

// fused: conv1(st_cl over [c,m]) + o-gate + h/diff write. grid 128
__global__ __launch_bounds__(256) void st_gate2c1_k(
    const float* __restrict__ c0, const float* __restrict__ m0,
    const float* __restrict__ wcl, const float* __restrict__ sth,
    const float* __restrict__ oS, float* __restrict__ h, float* __restrict__ diff) {
  int blk = blockIdx.x;
  int coB = blk & 3, pb = (blk >> 2) & 3, b = blk >> 4;
  int tid = threadIdx.x, px = pb * 256 + tid;
  float acc[16];
#pragma unroll
  for (int c = 0; c < 16; ++c) acc[c] = 0.f;
  const float* ib1 = c0 + (size_t)b * 65536 + px;
  const float* ib2 = m0 + (size_t)b * 65536 + px;
  for (int ci = 0; ci < 64; ++ci) {
    float v1 = ib1[ci * 1024], v2 = ib2[ci * 1024];
    const float* w1 = wcl + (size_t)ci * 64 + coB * 16;
    const float* w2 = wcl + (size_t)(64 + ci) * 64 + coB * 16;
#pragma unroll
    for (int c = 0; c < 16; ++c) {
      acc[c] = fmaf(w1[c], v1, acc[c]);
      acc[c] = fmaf(w2[c], v2, acc[c]);
    }
  }
#pragma unroll
  for (int c = 0; c < 16; ++c) {
    int co = coB * 16 + c;
    size_t o = (size_t)co * 1024 + px;
    float sto = sth[(size_t)b * 262144 + 196608 + o];
    float hn = sigf(sto + oS[(size_t)b * 65536 + o]) * tanhf(acc[c]);
    size_t ho = (size_t)b * 65536 + o;
    float old = h[ho];
    h[ho] = hn;
    diff[ho] = hn - old;
  }
}

// MN = A + B, chunks i,g,f,o
__global__ void mimn_gate_k(const float* __restrict__ A, const float* __restrict__ Bq,
                            float* __restrict__ dh, float* __restrict__ dc,
                            const float* __restrict__ ctw, const float* __restrict__ ocw) {
  int idx = blockIdx.x * 256 + threadIdx.x;
  int b = idx >> 16, r = idx & 65535;
  const float* a = A + (size_t)b * 262144 + r;
  const float* q = Bq + (size_t)b * 262144 + r;
  float i_ = a[0] + q[0], g_ = a[65536] + q[65536];
  float f_ = a[131072] + q[131072], o_ = a[196608] + q[196608];
  float c0 = dc[idx];
  float cn = sigf(f_ + c0 * ctw[65536 + r] + 1.f) * c0 +
             sigf(i_ + c0 * ctw[r]) * tanhf(g_);
  float hn = sigf(o_ + cn * ocw[r]) * tanhf(cn);
  dc[idx] = cn;
  dh[idx] = hn;
}

// S:i,g,f,o  T:i,g,o  X:i,g,f,o  QH/QX:i,g,f,o (summed)
__global__ void mb_gate1_k(const float* __restrict__ Sb, const float* __restrict__ Tb,
                           const float* __restrict__ Xb, const float* __restrict__ QH,
                           const float* __restrict__ QX, float* __restrict__ m,
                           float* __restrict__ c, float* __restrict__ cc,
                           const float* __restrict__ ctw, const float* __restrict__ ocw) {
  int idx = blockIdx.x * 256 + threadIdx.x;
  int b = idx >> 16, r = idx & 65535;
  const float* sb = Sb + (size_t)b * 262144 + r;
  const float* tb = Tb + (size_t)b * 196608 + r;
  const float* xb = Xb + (size_t)b * 262144 + r;
  const float* qh = QH + (size_t)b * 262144 + r;
  const float* qx = QX + (size_t)b * 262144 + r;
  float i_s = sb[0], g_s = sb[65536], f_s = sb[131072];
  float i_t = tb[0], g_t = tb[65536];
  float i_x = xb[0], g_x = xb[65536], f_x = xb[131072];
  float m0 = m[idx];
  float nm = sigf(f_x + f_s + 1.f) * m0 + sigf(i_x + i_s) * tanhf(g_x + g_s);
  float q_i = qh[0] + qx[0], q_g = qh[65536] + qx[65536];
  float q_f = qh[131072] + qx[131072], q_o = qh[196608] + qx[196608];
  float cc0 = cc[idx];
  float mims = sigf(q_f + cc0 * ctw[65536 + r] + 1.f) * cc0 +
               sigf(q_i + cc0 * ctw[r]) * tanhf(q_g);
  float h2 = sigf(q_o + mims * ocw[r]) * tanhf(mims);
  float nc = h2 + sigf(i_x + i_t) * tanhf(g_x + g_t);
  m[idx] = nm;
  c[idx] = nc;
  cc[idx] = mims;
}

// fused conv1(mb_last over [cI,m0]) + 3-term output gate. grid 128
__global__ __launch_bounds__(256) void mb_gate2c1_k(
    const float* __restrict__ cI, const float* __restrict__ m0,
    const float* __restrict__ wl, const float* __restrict__ Sb,
    const float* __restrict__ Tb, const float* __restrict__ Xb,
    float* __restrict__ h) {
  int blk = blockIdx.x;
  int coB = blk & 3, pb = (blk >> 2) & 3, b = blk >> 4;
  int tid = threadIdx.x, px = pb * 256 + tid;
  float acc[16];
#pragma unroll
  for (int c = 0; c < 16; ++c) acc[c] = 0.f;
  const float* ib1 = cI + (size_t)b * 65536 + px;
  const float* ib2 = m0 + (size_t)b * 65536 + px;
  for (int ci = 0; ci < 64; ++ci) {
    float v1 = ib1[ci * 1024], v2 = ib2[ci * 1024];
    const float* w1 = wl + (size_t)ci * 64 + coB * 16;
    const float* w2 = wl + (size_t)(64 + ci) * 64 + coB * 16;
#pragma unroll
    for (int c = 0; c < 16; ++c) {
      acc[c] = fmaf(w1[c], v1, acc[c]);
      acc[c] = fmaf(w2[c], v2, acc[c]);
    }
  }
#pragma unroll
  for (int c = 0; c < 16; ++c) {
    int co = coB * 16 + c;
    size_t o = (size_t)co * 1024 + px;
    float osum = Xb[(size_t)b * 262144 + 196608 + o] +
                 Tb[(size_t)b * 196608 + 131072 + o] +
                 Sb[(size_t)b * 262144 + 196608 + o];
    h[(size_t)b * 65536 + o] = sigf(osum) * tanhf(acc[c]);
  }
}

// final conv1 w_last + unpatchify. grid 32
__global__ __launch_bounds__(256) void xgen_k(const float* __restrict__ h3,
                                              const float* __restrict__ wwl,
                                              float* __restrict__ xg,
                                              float* __restrict__ out, int t) {
  int blk = blockIdx.x;
  int pb = blk & 3, b = blk >> 2;
  int tid = threadIdx.x, px = pb * 256 + tid;
  float acc[16];
#pragma unroll
  for (int c = 0; c < 16; ++c) acc[c] = 0.f;
  const float* ib = h3 + (size_t)b * 65536 + px;
  for (int ci = 0; ci < 64; ++ci) {
    float v = ib[ci * 1024];
    const float* w = wwl + (size_t)ci * 16;
#pragma unroll
    for (int c = 0; c < 16; ++c) acc[c] = fmaf(w[c], v, acc[c]);
  }
  int y = px >> 5, x = px & 31;
#pragma unroll
  for (int c = 0; c < 16; ++c) {
    xg[(size_t)b * 16384 + (size_t)c * 1024 + px] = acc[c];
    if (t >= 9) {
      int py = c >> 2, pxs = c & 3;
      out[((size_t)b * 10 + (t - 9)) * 16384 + (y * 4 + py) * 128 + (x * 4 + pxs)] =
          acc[c];
    }
  }
}

// ---------------------------------------------------------------------------
extern "C" void kernel_launch(void* const* d_in, const int* in_sizes, int n_in,
                              void* d_out, int out_size, void* d_ws, size_t ws_size,
                              hipStream_t stream) {
  const float* frames0 = (const float*)d_in[0];
  const float* st_cx = (const float*)d_in[2];
  const float* st_ch = (const float*)d_in[3];
  const float* st_cm = (const float*)d_in[4];
  const float* st_co = (const float*)d_in[5];
  const float* st_cl = (const float*)d_in[6];
  const float* mb_t = (const float*)d_in[7];
  const float* mb_s = (const float*)d_in[8];
  const float* mb_x = (const float*)d_in[9];
  const float* mb_mh = (const float*)d_in[10];
  const float* mb_mx = (const float*)d_in[11];
  const float* mb_ctw = (const float*)d_in[12];
  const float* mb_ocw = (const float*)d_in[13];
  const float* mb_last = (const float*)d_in[14];
  const float* mn_ch = (const float*)d_in[15];
  const float* mn_cx = (const float*)d_in[16];
  const float* mn_ctw = (const float*)d_in[17];
  const float* mn_ocw = (const float*)d_in[18];
  const float* w_last = (const float*)d_in[19];
  float* out = (float*)d_out;

  float* ws = (float*)d_ws;
  size_t off = 0;
  auto A_ = [&](size_t n) { float* p = ws + off; off += n; return p; };
  float* hs[4]; for (int i = 0; i < 4; ++i) hs[i] = A_(S);
  float* cs[4]; for (int i = 0; i < 4; ++i) cs[i] = A_(S);
  float* memb = A_(S);
  float* dh[3]; for (int i = 0; i < 3; ++i) dh[i] = A_(S);
  float* dcb[3]; for (int i = 0; i < 3; ++i) dcb[i] = A_(S);
  float* ccb[3]; for (int i = 0; i < 3; ++i) ccb[i] = A_(S);
  float* diffb = A_(S);
  size_t zeroFloats = off;  // 19*S
  float* xgen = A_(131072);
  float* netb = A_(131072);
  float* R1 = A_(4 * S);    // STH / MNa / QX
  float* RB = A_(4 * S);    // MNb
  float* R2 = A_(3 * S);    // STM
  float* R2L[3]; for (int i = 0; i < 3; ++i) R2L[i] = A_(3 * S);  // T per layer
  float* R3 = A_(4 * S);    // X
  float* R5 = A_(4 * S);    // Sconv
  float* RML[3]; for (int i = 0; i < 3; ++i) RML[i] = A_(4 * S);  // MH per layer
  float* B64a = A_(S);      // STO
  float* wtmbl[3]; for (int li = 0; li < 3; ++li) wtmbl[li] = A_(8192);
  float* wtcl = A_(8192);
  float* wtwl = A_(1024);
  us* warena = (us*)(ws + off);

  size_t wOff = 0;
  auto alloc = [&](int taps, int KS) {
    size_t o = wOff;
    wOff += (size_t)2 * taps * KS * 2048;
    return o;
  };
  size_t oSTH0n = alloc(25, 1), oSTH0h = alloc(25, 4);
  size_t oSTH1n = alloc(25, 1), oSTH1h = alloc(25, 4);
  size_t oSTM0n = alloc(25, 1), oSTM0m = alloc(25, 4);
  size_t oSTM1n = alloc(25, 1), oSTM1m = alloc(25, 4);
  size_t oSTOa = alloc(25, 4), oSTOb = alloc(25, 4);
  size_t oMNa0[3], oMNa1[3], oMNb0[3], oMNb1[3], oS0[3], oS1[3], oT0[3], oT1[3],
      oX0[3], oX1[3], oMH0[3], oMH1[3], oMX0[3], oMX1[3];
  for (int li = 0; li < 3; ++li) {
    oMNa0[li] = alloc(25, 4); oMNa1[li] = alloc(25, 4);
    oMNb0[li] = alloc(25, 4); oMNb1[li] = alloc(25, 4);
    oS0[li] = alloc(25, 4); oS1[li] = alloc(25, 4);
    oT0[li] = alloc(25, 4); oT1[li] = alloc(25, 4);
    oX0[li] = alloc(25, 4); oX1[li] = alloc(25, 4);
    oMH0[li] = alloc(25, 4); oMH1[li] = alloc(25, 4);
    oMX0[li] = alloc(25, 4); oMX1[li] = alloc(25, 4);
  }
  if (ws_size < off * sizeof(float) + wOff * sizeof(us)) return;

  hipMemsetAsync(ws, 0, zeroFloats * sizeof(float), stream);
  hipMemsetAsync(warena, 0, wOff * sizeof(us), stream);

  auto packL = [&](size_t dstOff, const float* src, int srcRow0, int nRows,
                   int dstRow0, int ciBase, int cinSrc, int taps, int KS) {
    int total = taps * KS * 4 * 64;
    pack_k<<<(total + 255) / 256, 256, 0, stream>>>(warena + dstOff, src, srcRow0,
                                                    nRows, dstRow0, ciBase, cinSrc,
                                                    taps, KS);
  };
  // st_cx rows: i(0) f(64) g(128) i'(192) f'(256) g'(320) o(384)
  packL(oSTH0n, st_cx, 0, 128, 0, 0, 16, 25, 1);
  packL(oSTH0h, st_ch, 0, 128, 0, 0, 64, 25, 4);
  packL(oSTH1n, st_cx, 128, 64, 0, 0, 16, 25, 1);
  packL(oSTH1n, st_cx, 384, 64, 64, 0, 16, 25, 1);
  packL(oSTH1h, st_ch, 128, 128, 0, 0, 64, 25, 4);
  packL(oSTM0n, st_cx, 192, 128, 0, 0, 16, 25, 1);
  packL(oSTM0m, st_cm, 0, 128, 0, 0, 64, 25, 4);
  packL(oSTM1n, st_cx, 320, 64, 0, 0, 16, 25, 1);
  packL(oSTM1m, st_cm, 128, 64, 0, 0, 64, 25, 4);
  packL(oSTOa, st_co, 0, 64, 0, 0, 128, 25, 4);
  packL(oSTOb, st_co, 0, 64, 0, 64, 128, 25, 4);
  for (int li = 0; li < 3; ++li) {
    const float* ch = mn_ch + (size_t)li * 409600;
    const float* cx = mn_cx + (size_t)li * 409600;
    const float* mbs = mb_s + (size_t)li * 409600;
    const float* mbt = mb_t + (size_t)li * 307200;
    const float* mbx = mb_x + (size_t)li * 409600;
    const float* mmh = mb_mh + (size_t)li * 409600;
    const float* mmx = mb_mx + (size_t)li * 409600;
    packL(oMNa0[li], ch, 0, 128, 0, 0, 64, 25, 4);
    packL(oMNa1[li], ch, 128, 128, 0, 0, 64, 25, 4);
    packL(oMNb0[li], cx, 0, 128, 0, 0, 64, 25, 4);
    packL(oMNb1[li], cx, 128, 128, 0, 0, 64, 25, 4);
    packL(oS0[li], mbs, 0, 128, 0, 0, 64, 25, 4);
    packL(oS1[li], mbs, 128, 128, 0, 0, 64, 25, 4);
    packL(oT0[li], mbt, 0, 128, 0, 0, 64, 25, 4);
    packL(oT1[li], mbt, 128, 64, 0, 0, 64, 25, 4);
    packL(oX0[li], mbx, 0, 128, 0, 0, 64, 25, 4);
    packL(oX1[li], mbx, 128, 128, 0, 0, 64, 25, 4);
    packL(oMH0[li], mmh, 0, 128, 0, 0, 64, 25, 4);
    packL(oMH1[li], mmh, 128, 128, 0, 0, 64, 25, 4);
    packL(oMX0[li], mmx, 0, 128, 0, 0, 64, 25, 4);
    packL(oMX1[li], mmx, 128, 128, 0, 0, 64, 25, 4);
    tr1_k<<<32, 256, 0, stream>>>(mb_last + (size_t)li * 8192, wtmbl[li], 128, 64);
  }
  tr1_k<<<32, 256, 0, stream>>>(st_cl, wtcl, 128, 64);
  tr1_k<<<4, 256, 0, stream>>>(w_last, wtwl, 64, 16);

  auto mkj = [&](const float* x0, size_t w0, int cin0, const float* x1, size_t w1,
                 int cin1, int taps, float* o, int outCo, int coBase, int coCnt) {
    Job j;
    j.x0 = x0; j.w0 = warena + w0; j.cin0 = cin0;
    j.x1 = x1; j.w1 = warena + w1; j.cin1 = cin1;
    j.taps = taps; j.out = o; j.outCo = outCo; j.coBase = coBase; j.coCnt = coCnt;
    return j;
  };
  auto launchB = [&](Batch& bt) {
    convmf6_k<<<bt.n * 64, 256, 0, stream>>>(bt);
  };

  for (int t = 0; t < 19; ++t) {
    const float* stIn = (t < 10) ? netb : xgen;
    if (t < 10) build_net_k<<<512, 256, 0, stream>>>(frames0, netb, t);
    {  // step-leading batch: STH+STM + all 3 layers' T+MH -> 16 jobs
      Batch P; P.n = 16;
      P.j[0] = mkj(stIn, oSTH0n, 16, hs[0], oSTH0h, 64, 25, R1, 256, 0, 128);
      P.j[1] = mkj(stIn, oSTH1n, 16, hs[0], oSTH1h, 64, 25, R1, 256, 128, 128);
      P.j[2] = mkj(stIn, oSTM0n, 16, memb, oSTM0m, 64, 25, R2, 192, 0, 128);
      P.j[3] = mkj(stIn, oSTM1n, 16, memb, oSTM1m, 64, 25, R2, 192, 128, 64);
      for (int li = 0; li < 3; ++li) {
        int i = li + 1;
        P.j[4 + li * 4 + 0] = mkj(hs[i], oT0[li], 64, nullptr, 0, 0, 25,
                                  R2L[li], 192, 0, 128);
        P.j[4 + li * 4 + 1] = mkj(hs[i], oT1[li], 64, nullptr, 0, 0, 25,
                                  R2L[li], 192, 128, 64);
        P.j[4 + li * 4 + 2] = mkj(cs[i], oMH0[li], 64, nullptr, 0, 0, 25,
                                  RML[li], 256, 0, 128);
        P.j[4 + li * 4 + 3] = mkj(cs[i], oMH1[li], 64, nullptr, 0, 0, 25,
                                  RML[li], 256, 128, 128);
      }
      launchB(P);
    }
    st_gate1_k<<<2048, 256, 0, stream>>>(R1, R2, cs[0], memb);
    {  // STO
      Batch P; P.n = 1;
      P.j[0] = mkj(cs[0], oSTOa, 64, memb, oSTOb, 64, 25, B64a, 64, 0, 64);
      launchB(P);
    }
    st_gate2c1_k<<<128, 256, 0, stream>>>(cs[0], memb, wtcl, R1, B64a, hs[0], diffb);

    for (int i = 1; i < 4; ++i) {
      int li = i - 1;
      const float* din = (i == 1) ? diffb : dh[i - 2];
      {  // A1: MNa + MNb + S + X -> 8 equal 64-ci jobs, one per XCD
        Batch P; int n = 0;
        if (t >= 1) {
          P.j[n++] = mkj(dh[li], oMNa0[li], 64, nullptr, 0, 0, 25, R1, 256, 0, 128);
          P.j[n++] = mkj(dh[li], oMNa1[li], 64, nullptr, 0, 0, 25, R1, 256, 128, 128);
          P.j[n++] = mkj(din, oMNb0[li], 64, nullptr, 0, 0, 25, RB, 256, 0, 128);
          P.j[n++] = mkj(din, oMNb1[li], 64, nullptr, 0, 0, 25, RB, 256, 128, 128);
        }
        P.j[n++] = mkj(memb, oS0[li], 64, nullptr, 0, 0, 25, R5, 256, 0, 128);
        P.j[n++] = mkj(memb, oS1[li], 64, nullptr, 0, 0, 25, R5, 256, 128, 128);
        P.j[n++] = mkj(hs[i - 1], oX0[li], 64, nullptr, 0, 0, 25, R3, 256, 0, 128);
        P.j[n++] = mkj(hs[i - 1], oX1[li], 64, nullptr, 0, 0, 25, R3, 256, 128, 128);
        P.n = n;
        launchB(P);
      }
      if (t >= 1)
        mimn_gate_k<<<2048, 256, 0, stream>>>(R1, RB, dh[li], dcb[li],
                                              mn_ctw + (size_t)li * 131072,
                                              mn_ocw + (size_t)li * 65536);
      {  // MX (dh post-update; zeros at t=0 -> QX = 0, matches reference)
        Batch P; P.n = 2;
        P.j[0] = mkj(dh[li], oMX0[li], 64, nullptr, 0, 0, 25, R1, 256, 0, 128);
        P.j[1] = mkj(dh[li], oMX1[li], 64, nullptr, 0, 0, 25, R1, 256, 128, 128);
        launchB(P);
      }
      mb_gate1_k<<<2048, 256, 0, stream>>>(R5, R2L[li], R3, RML[li], R1, memb, cs[i],
                                           ccb[li], mb_ctw + (size_t)li * 131072,
                                           mb_ocw + (size_t)li * 65536);
      mb_gate2c1_k<<<128, 256, 0, stream>>>(cs[i], memb, wtmbl[li], R5, R2L[li], R3,
                                            hs[i]);
    }
    xgen_k<<<32, 256, 0, stream>>>(hs[3], wtwl, xgen, out, t);
  }
}

// Round 16
// 11921.827 us; speedup vs baseline: 1.2049x; 1.1244x over previous
//
#include <hip/hip_runtime.h>
#include <math.h>

// ---------------------------------------------------------------------------
// MIM RNN round 16: r15 (best, 13.40ms) + RPB=2 conv variant for the weak
// launches: MX (2 jobs -> 256 blocks) and STO split into 2 single-source
// jobs (256 blocks, partials summed in st_gate2c1). Depth-4 A prefetch,
// XCD-aware decode, split-bf16 (3 merged passes), XOR-swizzle LDS.
// ---------------------------------------------------------------------------

#define S 524288  // 8*64*1024
typedef unsigned short us;
typedef __attribute__((ext_vector_type(8))) short bf16x8;
typedef __attribute__((ext_vector_type(16))) float f32x16;

__device__ __forceinline__ float sigf(float x) { return 1.0f / (1.0f + expf(-x)); }
__device__ __forceinline__ us f2bf(float f) {
  unsigned u = __float_as_uint(f);
  u += 0x7fffu + ((u >> 16) & 1u);
  return (us)(u >> 16);
}
__device__ __forceinline__ float bf2f(us h) {
  return __uint_as_float(((unsigned)h) << 16);
}
#define MFMA __builtin_amdgcn_mfma_f32_32x32x16_bf16

struct Job {
  const float* x0; const us* w0; int cin0;
  const float* x1; const us* w1; int cin1;
  int taps; float* out; int outCo; int coBase; int coCnt;
};
struct Batch { Job j[16]; int n; };

// ---------------- weight prepack: W'[half][tap][ks][coB4][lane64][8] --------
__global__ void pack_k(us* dst, const float* src, int srcRow0, int nRows,
                       int dstRow0, int ciBase, int cinSrc, int taps, int KS) {
  int idx = blockIdx.x * 256 + threadIdx.x;
  int total = taps * KS * 4 * 64;
  if (idx >= total) return;
  int l = idx & 63, cb = (idx >> 6) & 3, rest = idx >> 8;
  int ks = rest % KS, tap = rest / KS;
  int co_d = cb * 32 + (l & 31);
  if (co_d < dstRow0 || co_d >= dstRow0 + nRows) return;
  int srcRow = srcRow0 + (co_d - dstRow0);
  size_t AH = (size_t)taps * KS * 2048;
  size_t base = ((size_t)(tap * KS + ks) * 4 + cb) * 512 + (size_t)l * 8;
#pragma unroll
  for (int j = 0; j < 8; ++j) {
    int ci = ciBase + ks * 16 + (l >> 5) * 8 + j;
    float v = src[((size_t)srcRow * cinSrc + ci) * taps + tap];
    us hi = f2bf(v);
    dst[base + j] = hi;
    dst[AH + base + j] = f2bf(v - bf2f(hi));
  }
}

__global__ void tr1_k(const float* __restrict__ src, float* __restrict__ dst,
                      int Cin, int Cout) {
  int idx = blockIdx.x * 256 + threadIdx.x;
  if (idx >= Cout * Cin) return;
  int ci = idx % Cin, co = idx / Cin;
  dst[(size_t)ci * Cout + co] = src[idx];
}

// ---------------------------------------------------------------------------
// Conv: block = 256 thr (4 waves) = 128co x (RPB*32)px (RPB img rows, stages
// RPB+4). Wave (wc,wr): 2 co-tiles x RPB/2 px-rows. Slice (tap,kk): 4 A-frag
// vectors + 2*JR B LDS reads -> 6*JR MFMA; A prefetch depth 4.
// ji = blk % n (XCD-resident weights).
template <int RPB>
__global__ __launch_bounds__(256, 2) void convmf6_k(Batch bt) {
  constexpr int NR = RPB + 4;     // staged rows
  constexpr int JR = RPB / 2;     // rows per wave
  constexpr int PXM = (RPB == 4) ? 7 : 15;
  constexpr int PXS = (RPB == 4) ? 3 : 4;
  int blk = blockIdx.x;
  int ji = blk % bt.n;
  int local = blk / bt.n;
  Job J = bt.j[ji];
  int pxg = local & PXM;
  int b = local >> PXS;
  int r0 = pxg * RPB;
  int tid = threadIdx.x, l = tid & 63, wv = tid >> 6;
  int wc = wv & 1, wr = wv >> 1;
  int lcol = l & 31, lg = l >> 5;

  __shared__ __align__(16) unsigned char lds[2][NR][2368];

  f32x16 acc[2][JR];
#pragma unroll
  for (int r = 0; r < 2; ++r)
#pragma unroll
    for (int j2 = 0; j2 < JR; ++j2)
#pragma unroll
      for (int q = 0; q < 16; ++q) acc[r][j2][q] = 0.f;

  if (tid < 32 * NR) {  // zero halo cols 0,1,34,35
    int e = tid;
    int hh = e & 1, sl = (e >> 1) & 3;
    int rq = e >> 3;
    int row = rq % NR, cx = rq / NR;
    int col = cx < 2 ? cx : 32 + cx;
    float4 z = {0.f, 0.f, 0.f, 0.f};
    *(float4*)&lds[hh][row][col * 64 + sl * 16] = z;
  }

  for (int s = 0; s < 2; ++s) {
    const float* X = s ? J.x1 : J.x0;
    const us* W = s ? J.w1 : J.w0;
    int cin = s ? J.cin1 : J.cin0;
    if (cin == 0) continue;
    int KS = cin >> 4;
    size_t AH = (size_t)J.taps * KS * 2048;
    int nst = (cin + 31) >> 5;
    for (int st = 0; st < nst; ++st) {
      int ciCnt = cin - st * 32;
      if (ciCnt > 32) ciCnt = 32;
      int kls = ciCnt >> 4;      // 1 or 2
      int kshift = kls >> 1;     // 0 or 1
      int NS = J.taps * kls;
      auto aaddr = [&](int u) {
        int tap = u >> kshift, kk = u & (kls - 1);
        return W + (((size_t)tap * KS + st * 2 + kk) * 4 + wc * 2) * 512 +
               (size_t)l * 8;
      };
      // depth-4 A prefetch sets (indices always compile-time constants)
      bf16x8 AH0[4], AH1[4], AL0[4], AL1[4];
      auto loadA0 = [&](int u) {
        const us* wp = aaddr(u);
        AH0[0] = *(const bf16x8*)wp; AH1[0] = *(const bf16x8*)(wp + 512);
        AL0[0] = *(const bf16x8*)(wp + AH); AL1[0] = *(const bf16x8*)(wp + AH + 512);
      };
      auto loadA1 = [&](int u) {
        const us* wp = aaddr(u);
        AH0[1] = *(const bf16x8*)wp; AH1[1] = *(const bf16x8*)(wp + 512);
        AL0[1] = *(const bf16x8*)(wp + AH); AL1[1] = *(const bf16x8*)(wp + AH + 512);
      };
      auto loadA2 = [&](int u) {
        const us* wp = aaddr(u);
        AH0[2] = *(const bf16x8*)wp; AH1[2] = *(const bf16x8*)(wp + 512);
        AL0[2] = *(const bf16x8*)(wp + AH); AL1[2] = *(const bf16x8*)(wp + AH + 512);
      };
      auto loadA3 = [&](int u) {
        const us* wp = aaddr(u);
        AH0[3] = *(const bf16x8*)wp; AH1[3] = *(const bf16x8*)(wp + 512);
        AL0[3] = *(const bf16x8*)(wp + AH); AL1[3] = *(const bf16x8*)(wp + AH + 512);
      };
      loadA0(0);
      if (NS > 1) loadA1(1);
      if (NS > 2) loadA2(2);
      if (NS > 3) loadA3(3);
      __syncthreads();
      // stage NR rows (r0-2 .. r0+NR-3) of up-to-32 ci, hi+lo halves
      for (int u = tid; u < NR * 128; u += 256) {
        int cp = u & 15;
        int xq = (u >> 4) & 7;
        int row = u >> 7;  // 0..NR-1
        if (2 * cp < ciCnt) {
          int gy = r0 - 2 + row;
          float4 v0 = {0.f, 0.f, 0.f, 0.f}, v1 = {0.f, 0.f, 0.f, 0.f};
          if ((unsigned)gy < 32u) {
            const float* p0 =
                X + (((size_t)b * cin + st * 32 + 2 * cp) << 10) + gy * 32 + xq * 4;
            v0 = *(const float4*)p0;
            v1 = *(const float4*)(p0 + 1024);
          }
          const float* e0 = (const float*)&v0;
          const float* e1 = (const float*)&v1;
          int slot = cp >> 2, boff = (cp & 3) * 4;
#pragma unroll
          for (int e = 0; e < 4; ++e) {
            int col = xq * 4 + 2 + e;
            int off2 = col * 64 + ((slot ^ ((col >> 1) & 3)) << 4) + boff;
            us h0 = f2bf(e0[e]);
            us h1 = f2bf(e1[e]);
            us lo0 = f2bf(e0[e] - bf2f(h0));
            us lo1 = f2bf(e1[e] - bf2f(h1));
            *(unsigned*)&lds[0][row][off2] = (unsigned)h0 | ((unsigned)h1 << 16);
            *(unsigned*)&lds[1][row][off2] = (unsigned)lo0 | ((unsigned)lo1 << 16);
          }
        }
      }
      __syncthreads();
      auto slice = [&](int u, bf16x8 ah0, bf16x8 ah1, bf16x8 al0, bf16x8 al1) {
        int tap = u >> kshift, kk = u & (kls - 1);
        int dy, dx;
        if (J.taps == 1) { dy = 2; dx = 2; }
        else { dy = tap / 5; dx = tap - dy * 5; }
        int col = lcol + dx, cOff = col * 64, swz = (col >> 1) & 3;
        int phys = (((kk * 2 + lg) ^ swz) << 4);
        bf16x8 bb[JR];
#pragma unroll
        for (int j2 = 0; j2 < JR; ++j2)
          bb[j2] = *(const bf16x8*)&lds[0][wr * JR + j2 + dy][cOff + phys];
#pragma unroll
        for (int j2 = 0; j2 < JR; ++j2) {
          acc[0][j2] = MFMA(ah0, bb[j2], acc[0][j2], 0, 0, 0);
          acc[1][j2] = MFMA(ah1, bb[j2], acc[1][j2], 0, 0, 0);
        }
#pragma unroll
        for (int j2 = 0; j2 < JR; ++j2) {
          acc[0][j2] = MFMA(al0, bb[j2], acc[0][j2], 0, 0, 0);
          acc[1][j2] = MFMA(al1, bb[j2], acc[1][j2], 0, 0, 0);
        }
#pragma unroll
        for (int j2 = 0; j2 < JR; ++j2)
          bb[j2] =
              *(const bf16x8*)(&lds[0][wr * JR + j2 + dy][cOff + phys] + NR * 2368);
#pragma unroll
        for (int j2 = 0; j2 < JR; ++j2) {
          acc[0][j2] = MFMA(ah0, bb[j2], acc[0][j2], 0, 0, 0);
          acc[1][j2] = MFMA(ah1, bb[j2], acc[1][j2], 0, 0, 0);
        }
      };
      for (int uu = 0; uu < NS; uu += 4) {
        slice(uu, AH0[0], AH1[0], AL0[0], AL1[0]);
        if (uu + 4 < NS) loadA0(uu + 4);
        if (uu + 1 < NS) {
          slice(uu + 1, AH0[1], AH1[1], AL0[1], AL1[1]);
          if (uu + 5 < NS) loadA1(uu + 5);
        }
        if (uu + 2 < NS) {
          slice(uu + 2, AH0[2], AH1[2], AL0[2], AL1[2]);
          if (uu + 6 < NS) loadA2(uu + 6);
        }
        if (uu + 3 < NS) {
          slice(uu + 3, AH0[3], AH1[3], AL0[3], AL1[3]);
          if (uu + 7 < NS) loadA3(uu + 7);
        }
      }
    }
  }
  // store: D col = lane&31 (px), row = (reg&3) + 8*(reg>>2) + 4*(lane>>5)
#pragma unroll
  for (int r = 0; r < 2; ++r) {
#pragma unroll
    for (int j2 = 0; j2 < JR; ++j2) {
      int prow = r0 + wr * JR + j2;
      float* op = J.out + (((size_t)b * J.outCo) << 10) + prow * 32 + lcol;
#pragma unroll
      for (int q = 0; q < 16; ++q) {
        int coLoc = wc * 64 + r * 32 + 4 * lg + (q & 3) + 8 * (q >> 2);
        if (coLoc < J.coCnt)
          op[(size_t)(J.coBase + coLoc) << 10] = acc[r][j2][q];
      }
    }
  }
}

// ---------------------------------------------------------------------------
__global__ void build_net_k(const float* __restrict__ frames0, float* __restrict__ net,
                            int t) {
  int idx = blockIdx.x * 256 + threadIdx.x;
  int b = idx >> 14, ch = (idx >> 10) & 15, p = idx & 1023;
  int y = p >> 5, x = p & 31, py = ch >> 2, px = ch & 3;
  net[idx] = frames0[((size_t)b * 10 + t) * 16384 + (y * 4 + py) * 128 + (x * 4 + px)];
}

// STH [b][256]: i,f,g,o ; STM [b][192]: i',f',g'
__global__ void st_gate1_k(const float* __restrict__ sth, const float* __restrict__ stm,
                           float* __restrict__ c, float* __restrict__ m) {
  int idx = blockIdx.x * 256 + threadIdx.x;
  int b = idx >> 16, r = idx & 65535;
  const float* hb = sth + (size_t)b * 262144 + r;
  const float* mb = stm + (size_t)b * 196608 + r;
  float cn = sigf(hb[65536] + 1.f) * c[idx] + sigf(hb[0]) * tanhf(hb[131072]);
  float mn = sigf(mb[65536] + 1.f) * m[idx] + sigf(mb[0]) * tanhf(mb[131072]);
  c[idx] = cn;
  m[idx] = mn;
}

// fused: conv1(st_cl over [c,m]) + o-gate + h/diff write. grid 128
__global__ __launch_bounds__(256) void st_gate2c1_k(
    const float* __restrict__ c0, const float* __restrict__ m0,
    const float* __restrict__ wcl, const float* __restrict__ sth,
    const float* __restrict__ oSa, const float* __restrict__ oSb,
    float* __restrict__ h, float* __restrict__ diff) {
  int blk = blockIdx.x;
  int coB = blk & 3, pb = (blk >> 2) & 3, b = blk >> 4;
  int tid = threadIdx.x, px = pb * 256 + tid;
  float acc[16];
#pragma unroll
  for (int c = 0; c < 16; ++c) acc[c] = 0.f;
  const float* ib1 = c0 + (size_t)b * 65536 + px;
  const float* ib2 = m0 + (size_t)b * 65536 + px;
  for (int ci = 0; ci < 64; ++ci) {
    float v1 = ib1[ci * 1024], v2 = ib2[ci * 1024];
    const float* w1 = wcl + (size_t)ci * 64 + coB * 16;
    const float* w2 = wcl + (size_t)(64 + ci) * 64 + coB * 16;
#pragma unroll
    for (int c = 0; c < 16; ++c) {
      acc[c] = fmaf(w1[c], v1, acc[c]);
      acc[c] = fmaf(w2[c], v2, acc[c]);
    }
  }
#pragma unroll
  for (int c = 0; c < 16; ++c) {
    int co = coB * 16 + c;
    size_t o = (size_t)co * 1024 + px;
    float sto = sth[(size_t)b * 262144 + 196608 + o];
    size_t ho = (size_t)b * 65536 + o;
    float hn = sigf(sto + oSa[ho] + oSb[ho]) * tanhf(acc[c]);
    float old = h[ho];
    h[ho] = hn;
    diff[ho] = hn - old;
  }
}

// MN = A + B, chunks i,g,f,o
__global__ void mimn_gate_k(const float* __restrict__ A, const float* __restrict__ Bq,
                            float* __restrict__ dh, float* __restrict__ dc,
                            const float* __restrict__ ctw, const float* __restrict__ ocw) {
  int idx = blockIdx.x * 256 + threadIdx.x;
  int b = idx >> 16, r = idx & 65535;
  const float* a = A + (size_t)b * 262144 + r;
  const float* q = Bq + (size_t)b * 262144 + r;
  float i_ = a[0] + q[0], g_ = a[65536] + q[65536];
  float f_ = a[131072] + q[131072], o_ = a[196608] + q[196608];
  float c0 = dc[idx];
  float cn = sigf(f_ + c0 * ctw[65536 + r] + 1.f) * c0 +
             sigf(i_ + c0 * ctw[r]) * tanhf(g_);
  float hn = sigf(o_ + cn * ocw[r]) * tanhf(cn);
  dc[idx] = cn;
  dh[idx] = hn;
}

// S:i,g,f,o  T:i,g,o  X:i,g,f,o  QH/QX:i,g,f,o (summed)
__global__ void mb_gate1_k(const float* __restrict__ Sb, const float* __restrict__ Tb,
                           const float* __restrict__ Xb, const float* __restrict__ QH,
                           const float* __restrict__ QX, float* __restrict__ m,
                           float* __restrict__ c, float* __restrict__ cc,
                           const float* __restrict__ ctw, const float* __restrict__ ocw) {
  int idx = blockIdx.x * 256 + threadIdx.x;
  int b = idx >> 16, r = idx & 65535;
  const float* sb = Sb + (size_t)b * 262144 + r;
  const float* tb = Tb + (size_t)b * 196608 + r;
  const float* xb = Xb + (size_t)b * 262144 + r;
  const float* qh = QH + (size_t)b * 262144 + r;
  const float* qx = QX + (size_t)b * 262144 + r;
  float i_s = sb[0], g_s = sb[65536], f_s = sb[131072];
  float i_t = tb[0], g_t = tb[65536];
  float i_x = xb[0], g_x = xb[65536], f_x = xb[131072];
  float m0 = m[idx];
  float nm = sigf(f_x + f_s + 1.f) * m0 + sigf(i_x + i_s) * tanhf(g_x + g_s);
  float q_i = qh[0] + qx[0], q_g = qh[65536] + qx[65536];
  float q_f = qh[131072] + qx[131072], q_o = qh[196608] + qx[196608];
  float cc0 = cc[idx];
  float mims = sigf(q_f + cc0 * ctw[65536 + r] + 1.f) * cc0 +
               sigf(q_i + cc0 * ctw[r]) * tanhf(q_g);
  float h2 = sigf(q_o + mims * ocw[r]) * tanhf(mims);
  float nc = h2 + sigf(i_x + i_t) * tanhf(g_x + g_t);
  m[idx] = nm;
  c[idx] = nc;
  cc[idx] = mims;
}

// fused conv1(mb_last over [cI,m0]) + 3-term output gate. grid 128
__global__ __launch_bounds__(256) void mb_gate2c1_k(
    const float* __restrict__ cI, const float* __restrict__ m0,
    const float* __restrict__ wl, const float* __restrict__ Sb,
    const float* __restrict__ Tb, const float* __restrict__ Xb,
    float* __restrict__ h) {
  int blk = blockIdx.x;
  int coB = blk & 3, pb = (blk >> 2) & 3, b = blk >> 4;
  int tid = threadIdx.x, px = pb * 256 + tid;
  float acc[16];
#pragma unroll
  for (int c = 0; c < 16; ++c) acc[c] = 0.f;
  const float* ib1 = cI + (size_t)b * 65536 + px;
  const float* ib2 = m0 + (size_t)b * 65536 + px;
  for (int ci = 0; ci < 64; ++ci) {
    float v1 = ib1[ci * 1024], v2 = ib2[ci * 1024];
    const float* w1 = wl + (size_t)ci * 64 + coB * 16;
    const float* w2 = wl + (size_t)(64 + ci) * 64 + coB * 16;
#pragma unroll
    for (int c = 0; c < 16; ++c) {
      acc[c] = fmaf(w1[c], v1, acc[c]);
      acc[c] = fmaf(w2[c], v2, acc[c]);
    }
  }
#pragma unroll
  for (int c = 0; c < 16; ++c) {
    int co = coB * 16 + c;
    size_t o = (size_t)co * 1024 + px;
    float osum = Xb[(size_t)b * 262144 + 196608 + o] +
                 Tb[(size_t)b * 196608 + 131072 + o] +
                 Sb[(size_t)b * 262144 + 196608 + o];
    h[(size_t)b * 65536 + o] = sigf(osum) * tanhf(acc[c]);
  }
}

// final conv1 w_last + unpatchify. grid 32
__global__ __launch_bounds__(256) void xgen_k(const float* __restrict__ h3,
                                              const float* __restrict__ wwl,
                                              float* __restrict__ xg,
                                              float* __restrict__ out, int t) {
  int blk = blockIdx.x;
  int pb = blk & 3, b = blk >> 2;
  int tid = threadIdx.x, px = pb * 256 + tid;
  float acc[16];
#pragma unroll
  for (int c = 0; c < 16; ++c) acc[c] = 0.f;
  const float* ib = h3 + (size_t)b * 65536 + px;
  for (int ci = 0; ci < 64; ++ci) {
    float v = ib[ci * 1024];
    const float* w = wwl + (size_t)ci * 16;
#pragma unroll
    for (int c = 0; c < 16; ++c) acc[c] = fmaf(w[c], v, acc[c]);
  }
  int y = px >> 5, x = px & 31;
#pragma unroll
  for (int c = 0; c < 16; ++c) {
    xg[(size_t)b * 16384 + (size_t)c * 1024 + px] = acc[c];
    if (t >= 9) {
      int py = c >> 2, pxs = c & 3;
      out[((size_t)b * 10 + (t - 9)) * 16384 + (y * 4 + py) * 128 + (x * 4 + pxs)] =
          acc[c];
    }
  }
}

// ---------------------------------------------------------------------------
extern "C" void kernel_launch(void* const* d_in, const int* in_sizes, int n_in,
                              void* d_out, int out_size, void* d_ws, size_t ws_size,
                              hipStream_t stream) {
  const float* frames0 = (const float*)d_in[0];
  const float* st_cx = (const float*)d_in[2];
  const float* st_ch = (const float*)d_in[3];
  const float* st_cm = (const float*)d_in[4];
  const float* st_co = (const float*)d_in[5];
  const float* st_cl = (const float*)d_in[6];
  const float* mb_t = (const float*)d_in[7];
  const float* mb_s = (const float*)d_in[8];
  const float* mb_x = (const float*)d_in[9];
  const float* mb_mh = (const float*)d_in[10];
  const float* mb_mx = (const float*)d_in[11];
  const float* mb_ctw = (const float*)d_in[12];
  const float* mb_ocw = (const float*)d_in[13];
  const float* mb_last = (const float*)d_in[14];
  const float* mn_ch = (const float*)d_in[15];
  const float* mn_cx = (const float*)d_in[16];
  const float* mn_ctw = (const float*)d_in[17];
  const float* mn_ocw = (const float*)d_in[18];
  const float* w_last = (const float*)d_in[19];
  float* out = (float*)d_out;

  float* ws = (float*)d_ws;
  size_t off = 0;
  auto A_ = [&](size_t n) { float* p = ws + off; off += n; return p; };
  float* hs[4]; for (int i = 0; i < 4; ++i) hs[i] = A_(S);
  float* cs[4]; for (int i = 0; i < 4; ++i) cs[i] = A_(S);
  float* memb = A_(S);
  float* dh[3]; for (int i = 0; i < 3; ++i) dh[i] = A_(S);
  float* dcb[3]; for (int i = 0; i < 3; ++i) dcb[i] = A_(S);
  float* ccb[3]; for (int i = 0; i < 3; ++i) ccb[i] = A_(S);
  float* diffb = A_(S);
  size_t zeroFloats = off;  // 19*S
  float* xgen = A_(131072);
  float* netb = A_(131072);
  float* R1 = A_(4 * S);    // STH / MNa / QX
  float* RB = A_(4 * S);    // MNb
  float* R2 = A_(3 * S);    // STM
  float* R2L[3]; for (int i = 0; i < 3; ++i) R2L[i] = A_(3 * S);  // T per layer
  float* R3 = A_(4 * S);    // X
  float* R5 = A_(4 * S);    // Sconv
  float* RML[3]; for (int i = 0; i < 3; ++i) RML[i] = A_(4 * S);  // MH per layer
  float* B64a = A_(S);      // STO partial (cs half)
  float* B64b = A_(S);      // STO partial (memb half)
  float* wtmbl[3]; for (int li = 0; li < 3; ++li) wtmbl[li] = A_(8192);
  float* wtcl = A_(8192);
  float* wtwl = A_(1024);
  us* warena = (us*)(ws + off);

  size_t wOff = 0;
  auto alloc = [&](int taps, int KS) {
    size_t o = wOff;
    wOff += (size_t)2 * taps * KS * 2048;
    return o;
  };
  size_t oSTH0n = alloc(25, 1), oSTH0h = alloc(25, 4);
  size_t oSTH1n = alloc(25, 1), oSTH1h = alloc(25, 4);
  size_t oSTM0n = alloc(25, 1), oSTM0m = alloc(25, 4);
  size_t oSTM1n = alloc(25, 1), oSTM1m = alloc(25, 4);
  size_t oSTOa = alloc(25, 4), oSTOb = alloc(25, 4);
  size_t oMNa0[3], oMNa1[3], oMNb0[3], oMNb1[3], oS0[3], oS1[3], oT0[3], oT1[3],
      oX0[3], oX1[3], oMH0[3], oMH1[3], oMX0[3], oMX1[3];
  for (int li = 0; li < 3; ++li) {
    oMNa0[li] = alloc(25, 4); oMNa1[li] = alloc(25, 4);
    oMNb0[li] = alloc(25, 4); oMNb1[li] = alloc(25, 4);
    oS0[li] = alloc(25, 4); oS1[li] = alloc(25, 4);
    oT0[li] = alloc(25, 4); oT1[li] = alloc(25, 4);
    oX0[li] = alloc(25, 4); oX1[li] = alloc(25, 4);
    oMH0[li] = alloc(25, 4); oMH1[li] = alloc(25, 4);
    oMX0[li] = alloc(25, 4); oMX1[li] = alloc(25, 4);
  }
  if (ws_size < off * sizeof(float) + wOff * sizeof(us)) return;

  hipMemsetAsync(ws, 0, zeroFloats * sizeof(float), stream);
  hipMemsetAsync(warena, 0, wOff * sizeof(us), stream);

  auto packL = [&](size_t dstOff, const float* src, int srcRow0, int nRows,
                   int dstRow0, int ciBase, int cinSrc, int taps, int KS) {
    int total = taps * KS * 4 * 64;
    pack_k<<<(total + 255) / 256, 256, 0, stream>>>(warena + dstOff, src, srcRow0,
                                                    nRows, dstRow0, ciBase, cinSrc,
                                                    taps, KS);
  };
  // st_cx rows: i(0) f(64) g(128) i'(192) f'(256) g'(320) o(384)
  packL(oSTH0n, st_cx, 0, 128, 0, 0, 16, 25, 1);
  packL(oSTH0h, st_ch, 0, 128, 0, 0, 64, 25, 4);
  packL(oSTH1n, st_cx, 128, 64, 0, 0, 16, 25, 1);
  packL(oSTH1n, st_cx, 384, 64, 64, 0, 16, 25, 1);
  packL(oSTH1h, st_ch, 128, 128, 0, 0, 64, 25, 4);
  packL(oSTM0n, st_cx, 192, 128, 0, 0, 16, 25, 1);
  packL(oSTM0m, st_cm, 0, 128, 0, 0, 64, 25, 4);
  packL(oSTM1n, st_cx, 320, 64, 0, 0, 16, 25, 1);
  packL(oSTM1m, st_cm, 128, 64, 0, 0, 64, 25, 4);
  packL(oSTOa, st_co, 0, 64, 0, 0, 128, 25, 4);
  packL(oSTOb, st_co, 0, 64, 0, 64, 128, 25, 4);
  for (int li = 0; li < 3; ++li) {
    const float* ch = mn_ch + (size_t)li * 409600;
    const float* cx = mn_cx + (size_t)li * 409600;
    const float* mbs = mb_s + (size_t)li * 409600;
    const float* mbt = mb_t + (size_t)li * 307200;
    const float* mbx = mb_x + (size_t)li * 409600;
    const float* mmh = mb_mh + (size_t)li * 409600;
    const float* mmx = mb_mx + (size_t)li * 409600;
    packL(oMNa0[li], ch, 0, 128, 0, 0, 64, 25, 4);
    packL(oMNa1[li], ch, 128, 128, 0, 0, 64, 25, 4);
    packL(oMNb0[li], cx, 0, 128, 0, 0, 64, 25, 4);
    packL(oMNb1[li], cx, 128, 128, 0, 0, 64, 25, 4);
    packL(oS0[li], mbs, 0, 128, 0, 0, 64, 25, 4);
    packL(oS1[li], mbs, 128, 128, 0, 0, 64, 25, 4);
    packL(oT0[li], mbt, 0, 128, 0, 0, 64, 25, 4);
    packL(oT1[li], mbt, 128, 64, 0, 0, 64, 25, 4);
    packL(oX0[li], mbx, 0, 128, 0, 0, 64, 25, 4);
    packL(oX1[li], mbx, 128, 128, 0, 0, 64, 25, 4);
    packL(oMH0[li], mmh, 0, 128, 0, 0, 64, 25, 4);
    packL(oMH1[li], mmh, 128, 128, 0, 0, 64, 25, 4);
    packL(oMX0[li], mmx, 0, 128, 0, 0, 64, 25, 4);
    packL(oMX1[li], mmx, 128, 128, 0, 0, 64, 25, 4);
    tr1_k<<<32, 256, 0, stream>>>(mb_last + (size_t)li * 8192, wtmbl[li], 128, 64);
  }
  tr1_k<<<32, 256, 0, stream>>>(st_cl, wtcl, 128, 64);
  tr1_k<<<4, 256, 0, stream>>>(w_last, wtwl, 64, 16);

  auto mkj = [&](const float* x0, size_t w0, int cin0, const float* x1, size_t w1,
                 int cin1, int taps, float* o, int outCo, int coBase, int coCnt) {
    Job j;
    j.x0 = x0; j.w0 = warena + w0; j.cin0 = cin0;
    j.x1 = x1; j.w1 = warena + w1; j.cin1 = cin1;
    j.taps = taps; j.out = o; j.outCo = outCo; j.coBase = coBase; j.coCnt = coCnt;
    return j;
  };
  auto launchB = [&](Batch& bt) {
    convmf6_k<4><<<bt.n * 64, 256, 0, stream>>>(bt);
  };
  auto launchB2 = [&](Batch& bt) {
    convmf6_k<2><<<bt.n * 128, 256, 0, stream>>>(bt);
  };

  for (int t = 0; t < 19; ++t) {
    const float* stIn = (t < 10) ? netb : xgen;
    if (t < 10) build_net_k<<<512, 256, 0, stream>>>(frames0, netb, t);
    {  // step-leading batch: STH+STM + all 3 layers' T+MH -> 16 jobs
      Batch P; P.n = 16;
      P.j[0] = mkj(stIn, oSTH0n, 16, hs[0], oSTH0h, 64, 25, R1, 256, 0, 128);
      P.j[1] = mkj(stIn, oSTH1n, 16, hs[0], oSTH1h, 64, 25, R1, 256, 128, 128);
      P.j[2] = mkj(stIn, oSTM0n, 16, memb, oSTM0m, 64, 25, R2, 192, 0, 128);
      P.j[3] = mkj(stIn, oSTM1n, 16, memb, oSTM1m, 64, 25, R2, 192, 128, 64);
      for (int li = 0; li < 3; ++li) {
        int i = li + 1;
        P.j[4 + li * 4 + 0] = mkj(hs[i], oT0[li], 64, nullptr, 0, 0, 25,
                                  R2L[li], 192, 0, 128);
        P.j[4 + li * 4 + 1] = mkj(hs[i], oT1[li], 64, nullptr, 0, 0, 25,
                                  R2L[li], 192, 128, 64);
        P.j[4 + li * 4 + 2] = mkj(cs[i], oMH0[li], 64, nullptr, 0, 0, 25,
                                  RML[li], 256, 0, 128);
        P.j[4 + li * 4 + 3] = mkj(cs[i], oMH1[li], 64, nullptr, 0, 0, 25,
                                  RML[li], 256, 128, 128);
      }
      launchB(P);
    }
    st_gate1_k<<<2048, 256, 0, stream>>>(R1, R2, cs[0], memb);
    {  // STO: 2 single-source jobs (partials), RPB=2 -> 256 blocks
      Batch P; P.n = 2;
      P.j[0] = mkj(cs[0], oSTOa, 64, nullptr, 0, 0, 25, B64a, 64, 0, 64);
      P.j[1] = mkj(memb, oSTOb, 64, nullptr, 0, 0, 25, B64b, 64, 0, 64);
      launchB2(P);
    }
    st_gate2c1_k<<<128, 256, 0, stream>>>(cs[0], memb, wtcl, R1, B64a, B64b, hs[0],
                                          diffb);

    for (int i = 1; i < 4; ++i) {
      int li = i - 1;
      const float* din = (i == 1) ? diffb : dh[i - 2];
      {  // A1: MNa + MNb + S + X -> 8 equal 64-ci jobs, one per XCD
        Batch P; int n = 0;
        if (t >= 1) {
          P.j[n++] = mkj(dh[li], oMNa0[li], 64, nullptr, 0, 0, 25, R1, 256, 0, 128);
          P.j[n++] = mkj(dh[li], oMNa1[li], 64, nullptr, 0, 0, 25, R1, 256, 128, 128);
          P.j[n++] = mkj(din, oMNb0[li], 64, nullptr, 0, 0, 25, RB, 256, 0, 128);
          P.j[n++] = mkj(din, oMNb1[li], 64, nullptr, 0, 0, 25, RB, 256, 128, 128);
        }
        P.j[n++] = mkj(memb, oS0[li], 64, nullptr, 0, 0, 25, R5, 256, 0, 128);
        P.j[n++] = mkj(memb, oS1[li], 64, nullptr, 0, 0, 25, R5, 256, 128, 128);
        P.j[n++] = mkj(hs[i - 1], oX0[li], 64, nullptr, 0, 0, 25, R3, 256, 0, 128);
        P.j[n++] = mkj(hs[i - 1], oX1[li], 64, nullptr, 0, 0, 25, R3, 256, 128, 128);
        P.n = n;
        launchB(P);
      }
      if (t >= 1)
        mimn_gate_k<<<2048, 256, 0, stream>>>(R1, RB, dh[li], dcb[li],
                                              mn_ctw + (size_t)li * 131072,
                                              mn_ocw + (size_t)li * 65536);
      {  // MX: RPB=2 -> 256 blocks (dh post-update; zeros at t=0 -> QX=0, OK)
        Batch P; P.n = 2;
        P.j[0] = mkj(dh[li], oMX0[li], 64, nullptr, 0, 0, 25, R1, 256, 0, 128);
        P.j[1] = mkj(dh[li], oMX1[li], 64, nullptr, 0, 0, 25, R1, 256, 128, 128);
        launchB2(P);
      }
      mb_gate1_k<<<2048, 256, 0, stream>>>(R5, R2L[li], R3, RML[li], R1, memb, cs[i],
                                           ccb[li], mb_ctw + (size_t)li * 131072,
                                           mb_ocw + (size_t)li * 65536);
      mb_gate2c1_k<<<128, 256, 0, stream>>>(cs[i], memb, wtmbl[li], R5, R2L[li], R3,
                                            hs[i]);
    }
    xgen_k<<<32, 256, 0, stream>>>(hs[3], wtwl, xgen, out, t);
  }
}

// Round 17
// 11894.236 us; speedup vs baseline: 1.2077x; 1.0023x over previous
//
#include <hip/hip_runtime.h>
#include <math.h>

// ---------------------------------------------------------------------------
// MIM RNN round 17: r16 (best, 11.92ms) + widened gate/conv1 kernels:
// st_gate2c1 & mb_gate2c1 -> 256 blocks x 128 thr (1 block/CU on ALL CUs),
// xgen -> 128 blocks x 64 thr. Conv machinery unchanged: depth-4 A prefetch,
// XCD-aware decode, split-bf16 (3 merged passes), XOR-swizzle LDS, RPB=2
// variant for STO/MX.
// ---------------------------------------------------------------------------

#define S 524288  // 8*64*1024
typedef unsigned short us;
typedef __attribute__((ext_vector_type(8))) short bf16x8;
typedef __attribute__((ext_vector_type(16))) float f32x16;

__device__ __forceinline__ float sigf(float x) { return 1.0f / (1.0f + expf(-x)); }
__device__ __forceinline__ us f2bf(float f) {
  unsigned u = __float_as_uint(f);
  u += 0x7fffu + ((u >> 16) & 1u);
  return (us)(u >> 16);
}
__device__ __forceinline__ float bf2f(us h) {
  return __uint_as_float(((unsigned)h) << 16);
}
#define MFMA __builtin_amdgcn_mfma_f32_32x32x16_bf16

struct Job {
  const float* x0; const us* w0; int cin0;
  const float* x1; const us* w1; int cin1;
  int taps; float* out; int outCo; int coBase; int coCnt;
};
struct Batch { Job j[16]; int n; };

// ---------------- weight prepack: W'[half][tap][ks][coB4][lane64][8] --------
__global__ void pack_k(us* dst, const float* src, int srcRow0, int nRows,
                       int dstRow0, int ciBase, int cinSrc, int taps, int KS) {
  int idx = blockIdx.x * 256 + threadIdx.x;
  int total = taps * KS * 4 * 64;
  if (idx >= total) return;
  int l = idx & 63, cb = (idx >> 6) & 3, rest = idx >> 8;
  int ks = rest % KS, tap = rest / KS;
  int co_d = cb * 32 + (l & 31);
  if (co_d < dstRow0 || co_d >= dstRow0 + nRows) return;
  int srcRow = srcRow0 + (co_d - dstRow0);
  size_t AH = (size_t)taps * KS * 2048;
  size_t base = ((size_t)(tap * KS + ks) * 4 + cb) * 512 + (size_t)l * 8;
#pragma unroll
  for (int j = 0; j < 8; ++j) {
    int ci = ciBase + ks * 16 + (l >> 5) * 8 + j;
    float v = src[((size_t)srcRow * cinSrc + ci) * taps + tap];
    us hi = f2bf(v);
    dst[base + j] = hi;
    dst[AH + base + j] = f2bf(v - bf2f(hi));
  }
}

__global__ void tr1_k(const float* __restrict__ src, float* __restrict__ dst,
                      int Cin, int Cout) {
  int idx = blockIdx.x * 256 + threadIdx.x;
  if (idx >= Cout * Cin) return;
  int ci = idx % Cin, co = idx / Cin;
  dst[(size_t)ci * Cout + co] = src[idx];
}

// ---------------------------------------------------------------------------
// Conv: block = 256 thr (4 waves) = 128co x (RPB*32)px (RPB img rows, stages
// RPB+4). Wave (wc,wr): 2 co-tiles x RPB/2 px-rows. Slice (tap,kk): 4 A-frag
// vectors + 2*JR B LDS reads -> 6*JR MFMA; A prefetch depth 4.
// ji = blk % n (XCD-resident weights).
template <int RPB>
__global__ __launch_bounds__(256, 2) void convmf6_k(Batch bt) {
  constexpr int NR = RPB + 4;     // staged rows
  constexpr int JR = RPB / 2;     // rows per wave
  constexpr int PXM = (RPB == 4) ? 7 : 15;
  constexpr int PXS = (RPB == 4) ? 3 : 4;
  int blk = blockIdx.x;
  int ji = blk % bt.n;
  int local = blk / bt.n;
  Job J = bt.j[ji];
  int pxg = local & PXM;
  int b = local >> PXS;
  int r0 = pxg * RPB;
  int tid = threadIdx.x, l = tid & 63, wv = tid >> 6;
  int wc = wv & 1, wr = wv >> 1;
  int lcol = l & 31, lg = l >> 5;

  __shared__ __align__(16) unsigned char lds[2][NR][2368];

  f32x16 acc[2][JR];
#pragma unroll
  for (int r = 0; r < 2; ++r)
#pragma unroll
    for (int j2 = 0; j2 < JR; ++j2)
#pragma unroll
      for (int q = 0; q < 16; ++q) acc[r][j2][q] = 0.f;

  if (tid < 32 * NR) {  // zero halo cols 0,1,34,35
    int e = tid;
    int hh = e & 1, sl = (e >> 1) & 3;
    int rq = e >> 3;
    int row = rq % NR, cx = rq / NR;
    int col = cx < 2 ? cx : 32 + cx;
    float4 z = {0.f, 0.f, 0.f, 0.f};
    *(float4*)&lds[hh][row][col * 64 + sl * 16] = z;
  }

  for (int s = 0; s < 2; ++s) {
    const float* X = s ? J.x1 : J.x0;
    const us* W = s ? J.w1 : J.w0;
    int cin = s ? J.cin1 : J.cin0;
    if (cin == 0) continue;
    int KS = cin >> 4;
    size_t AH = (size_t)J.taps * KS * 2048;
    int nst = (cin + 31) >> 5;
    for (int st = 0; st < nst; ++st) {
      int ciCnt = cin - st * 32;
      if (ciCnt > 32) ciCnt = 32;
      int kls = ciCnt >> 4;      // 1 or 2
      int kshift = kls >> 1;     // 0 or 1
      int NS = J.taps * kls;
      auto aaddr = [&](int u) {
        int tap = u >> kshift, kk = u & (kls - 1);
        return W + (((size_t)tap * KS + st * 2 + kk) * 4 + wc * 2) * 512 +
               (size_t)l * 8;
      };
      // depth-4 A prefetch sets (indices always compile-time constants)
      bf16x8 AH0[4], AH1[4], AL0[4], AL1[4];
      auto loadA0 = [&](int u) {
        const us* wp = aaddr(u);
        AH0[0] = *(const bf16x8*)wp; AH1[0] = *(const bf16x8*)(wp + 512);
        AL0[0] = *(const bf16x8*)(wp + AH); AL1[0] = *(const bf16x8*)(wp + AH + 512);
      };
      auto loadA1 = [&](int u) {
        const us* wp = aaddr(u);
        AH0[1] = *(const bf16x8*)wp; AH1[1] = *(const bf16x8*)(wp + 512);
        AL0[1] = *(const bf16x8*)(wp + AH); AL1[1] = *(const bf16x8*)(wp + AH + 512);
      };
      auto loadA2 = [&](int u) {
        const us* wp = aaddr(u);
        AH0[2] = *(const bf16x8*)wp; AH1[2] = *(const bf16x8*)(wp + 512);
        AL0[2] = *(const bf16x8*)(wp + AH); AL1[2] = *(const bf16x8*)(wp + AH + 512);
      };
      auto loadA3 = [&](int u) {
        const us* wp = aaddr(u);
        AH0[3] = *(const bf16x8*)wp; AH1[3] = *(const bf16x8*)(wp + 512);
        AL0[3] = *(const bf16x8*)(wp + AH); AL1[3] = *(const bf16x8*)(wp + AH + 512);
      };
      loadA0(0);
      if (NS > 1) loadA1(1);
      if (NS > 2) loadA2(2);
      if (NS > 3) loadA3(3);
      __syncthreads();
      // stage NR rows (r0-2 .. r0+NR-3) of up-to-32 ci, hi+lo halves
      for (int u = tid; u < NR * 128; u += 256) {
        int cp = u & 15;
        int xq = (u >> 4) & 7;
        int row = u >> 7;  // 0..NR-1
        if (2 * cp < ciCnt) {
          int gy = r0 - 2 + row;
          float4 v0 = {0.f, 0.f, 0.f, 0.f}, v1 = {0.f, 0.f, 0.f, 0.f};
          if ((unsigned)gy < 32u) {
            const float* p0 =
                X + (((size_t)b * cin + st * 32 + 2 * cp) << 10) + gy * 32 + xq * 4;
            v0 = *(const float4*)p0;
            v1 = *(const float4*)(p0 + 1024);
          }
          const float* e0 = (const float*)&v0;
          const float* e1 = (const float*)&v1;
          int slot = cp >> 2, boff = (cp & 3) * 4;
#pragma unroll
          for (int e = 0; e < 4; ++e) {
            int col = xq * 4 + 2 + e;
            int off2 = col * 64 + ((slot ^ ((col >> 1) & 3)) << 4) + boff;
            us h0 = f2bf(e0[e]);
            us h1 = f2bf(e1[e]);
            us lo0 = f2bf(e0[e] - bf2f(h0));
            us lo1 = f2bf(e1[e] - bf2f(h1));
            *(unsigned*)&lds[0][row][off2] = (unsigned)h0 | ((unsigned)h1 << 16);
            *(unsigned*)&lds[1][row][off2] = (unsigned)lo0 | ((unsigned)lo1 << 16);
          }
        }
      }
      __syncthreads();
      auto slice = [&](int u, bf16x8 ah0, bf16x8 ah1, bf16x8 al0, bf16x8 al1) {
        int tap = u >> kshift, kk = u & (kls - 1);
        int dy, dx;
        if (J.taps == 1) { dy = 2; dx = 2; }
        else { dy = tap / 5; dx = tap - dy * 5; }
        int col = lcol + dx, cOff = col * 64, swz = (col >> 1) & 3;
        int phys = (((kk * 2 + lg) ^ swz) << 4);
        bf16x8 bb[JR];
#pragma unroll
        for (int j2 = 0; j2 < JR; ++j2)
          bb[j2] = *(const bf16x8*)&lds[0][wr * JR + j2 + dy][cOff + phys];
#pragma unroll
        for (int j2 = 0; j2 < JR; ++j2) {
          acc[0][j2] = MFMA(ah0, bb[j2], acc[0][j2], 0, 0, 0);
          acc[1][j2] = MFMA(ah1, bb[j2], acc[1][j2], 0, 0, 0);
        }
#pragma unroll
        for (int j2 = 0; j2 < JR; ++j2) {
          acc[0][j2] = MFMA(al0, bb[j2], acc[0][j2], 0, 0, 0);
          acc[1][j2] = MFMA(al1, bb[j2], acc[1][j2], 0, 0, 0);
        }
#pragma unroll
        for (int j2 = 0; j2 < JR; ++j2)
          bb[j2] =
              *(const bf16x8*)(&lds[0][wr * JR + j2 + dy][cOff + phys] + NR * 2368);
#pragma unroll
        for (int j2 = 0; j2 < JR; ++j2) {
          acc[0][j2] = MFMA(ah0, bb[j2], acc[0][j2], 0, 0, 0);
          acc[1][j2] = MFMA(ah1, bb[j2], acc[1][j2], 0, 0, 0);
        }
      };
      for (int uu = 0; uu < NS; uu += 4) {
        slice(uu, AH0[0], AH1[0], AL0[0], AL1[0]);
        if (uu + 4 < NS) loadA0(uu + 4);
        if (uu + 1 < NS) {
          slice(uu + 1, AH0[1], AH1[1], AL0[1], AL1[1]);
          if (uu + 5 < NS) loadA1(uu + 5);
        }
        if (uu + 2 < NS) {
          slice(uu + 2, AH0[2], AH1[2], AL0[2], AL1[2]);
          if (uu + 6 < NS) loadA2(uu + 6);
        }
        if (uu + 3 < NS) {
          slice(uu + 3, AH0[3], AH1[3], AL0[3], AL1[3]);
          if (uu + 7 < NS) loadA3(uu + 7);
        }
      }
    }
  }
  // store: D col = lane&31 (px), row = (reg&3) + 8*(reg>>2) + 4*(lane>>5)
#pragma unroll
  for (int r = 0; r < 2; ++r) {
#pragma unroll
    for (int j2 = 0; j2 < JR; ++j2) {
      int prow = r0 + wr * JR + j2;
      float* op = J.out + (((size_t)b * J.outCo) << 10) + prow * 32 + lcol;
#pragma unroll
      for (int q = 0; q < 16; ++q) {
        int coLoc = wc * 64 + r * 32 + 4 * lg + (q & 3) + 8 * (q >> 2);
        if (coLoc < J.coCnt)
          op[(size_t)(J.coBase + coLoc) << 10] = acc[r][j2][q];
      }
    }
  }
}

// ---------------------------------------------------------------------------
__global__ void build_net_k(const float* __restrict__ frames0, float* __restrict__ net,
                            int t) {
  int idx = blockIdx.x * 256 + threadIdx.x;
  int b = idx >> 14, ch = (idx >> 10) & 15, p = idx & 1023;
  int y = p >> 5, x = p & 31, py = ch >> 2, px = ch & 3;
  net[idx] = frames0[((size_t)b * 10 + t) * 16384 + (y * 4 + py) * 128 + (x * 4 + px)];
}

// STH [b][256]: i,f,g,o ; STM [b][192]: i',f',g'
__global__ void st_gate1_k(const float* __restrict__ sth, const float* __restrict__ stm,
                           float* __restrict__ c, float* __restrict__ m) {
  int idx = blockIdx.x * 256 + threadIdx.x;
  int b = idx >> 16, r = idx & 65535;
  const float* hb = sth + (size_t)b * 262144 + r;
  const float* mb = stm + (size_t)b * 196608 + r;
  float cn = sigf(hb[65536] + 1.f) * c[idx] + sigf(hb[0]) * tanhf(hb[131072]);
  float mn = sigf(mb[65536] + 1.f) * m[idx] + sigf(mb[0]) * tanhf(mb[131072]);
  c[idx] = cn;
  m[idx] = mn;
}

// fused: conv1(st_cl over [c,m]) + o-gate + h/diff write. grid 256 x 128 thr
__global__ __launch_bounds__(128) void st_gate2c1_k(
    const float* __restrict__ c0, const float* __restrict__ m0,
    const float* __restrict__ wcl, const float* __restrict__ sth,
    const float* __restrict__ oSa, const float* __restrict__ oSb,
    float* __restrict__ h, float* __restrict__ diff) {
  int blk = blockIdx.x;
  int coB = blk & 3, pb = (blk >> 2) & 7, b = blk >> 5;
  int tid = threadIdx.x, px = pb * 128 + tid;
  float acc[16];
#pragma unroll
  for (int c = 0; c < 16; ++c) acc[c] = 0.f;
  const float* ib1 = c0 + (size_t)b * 65536 + px;
  const float* ib2 = m0 + (size_t)b * 65536 + px;
  for (int ci = 0; ci < 64; ++ci) {
    float v1 = ib1[ci * 1024], v2 = ib2[ci * 1024];
    const float* w1 = wcl + (size_t)ci * 64 + coB * 16;
    const float* w2 = wcl + (size_t)(64 + ci) * 64 + coB * 16;
#pragma unroll
    for (int c = 0; c < 16; ++c) {
      acc[c] = fmaf(w1[c], v1, acc[c]);
      acc[c] = fmaf(w2[c], v2, acc[c]);
    }
  }
#pragma unroll
  for (int c = 0; c < 16; ++c) {
    int co = coB * 16 + c;
    size_t o = (size_t)co * 1024 + px;
    float sto = sth[(size_t)b * 262144 + 196608 + o];
    size_t ho = (size_t)b * 65536 + o;
    float hn = sigf(sto + oSa[ho] + oSb[ho]) * tanhf(acc[c]);
    float old = h[ho];
    h[ho] = hn;
    diff[ho] = hn - old;
  }
}

// MN = A + B, chunks i,g,f,o
__global__ void mimn_gate_k(const float* __restrict__ A, const float* __restrict__ Bq,
                            float* __restrict__ dh, float* __restrict__ dc,
                            const float* __restrict__ ctw, const float* __restrict__ ocw) {
  int idx = blockIdx.x * 256 + threadIdx.x;
  int b = idx >> 16, r = idx & 65535;
  const float* a = A + (size_t)b * 262144 + r;
  const float* q = Bq + (size_t)b * 262144 + r;
  float i_ = a[0] + q[0], g_ = a[65536] + q[65536];
  float f_ = a[131072] + q[131072], o_ = a[196608] + q[196608];
  float c0 = dc[idx];
  float cn = sigf(f_ + c0 * ctw[65536 + r] + 1.f) * c0 +
             sigf(i_ + c0 * ctw[r]) * tanhf(g_);
  float hn = sigf(o_ + cn * ocw[r]) * tanhf(cn);
  dc[idx] = cn;
  dh[idx] = hn;
}

// S:i,g,f,o  T:i,g,o  X:i,g,f,o  QH/QX:i,g,f,o (summed)
__global__ void mb_gate1_k(const float* __restrict__ Sb, const float* __restrict__ Tb,
                           const float* __restrict__ Xb, const float* __restrict__ QH,
                           const float* __restrict__ QX, float* __restrict__ m,
                           float* __restrict__ c, float* __restrict__ cc,
                           const float* __restrict__ ctw, const float* __restrict__ ocw) {
  int idx = blockIdx.x * 256 + threadIdx.x;
  int b = idx >> 16, r = idx & 65535;
  const float* sb = Sb + (size_t)b * 262144 + r;
  const float* tb = Tb + (size_t)b * 196608 + r;
  const float* xb = Xb + (size_t)b * 262144 + r;
  const float* qh = QH + (size_t)b * 262144 + r;
  const float* qx = QX + (size_t)b * 262144 + r;
  float i_s = sb[0], g_s = sb[65536], f_s = sb[131072];
  float i_t = tb[0], g_t = tb[65536];
  float i_x = xb[0], g_x = xb[65536], f_x = xb[131072];
  float m0 = m[idx];
  float nm = sigf(f_x + f_s + 1.f) * m0 + sigf(i_x + i_s) * tanhf(g_x + g_s);
  float q_i = qh[0] + qx[0], q_g = qh[65536] + qx[65536];
  float q_f = qh[131072] + qx[131072], q_o = qh[196608] + qx[196608];
  float cc0 = cc[idx];
  float mims = sigf(q_f + cc0 * ctw[65536 + r] + 1.f) * cc0 +
               sigf(q_i + cc0 * ctw[r]) * tanhf(q_g);
  float h2 = sigf(q_o + mims * ocw[r]) * tanhf(mims);
  float nc = h2 + sigf(i_x + i_t) * tanhf(g_x + g_t);
  m[idx] = nm;
  c[idx] = nc;
  cc[idx] = mims;
}

// fused conv1(mb_last over [cI,m0]) + 3-term output gate. grid 256 x 128 thr
__global__ __launch_bounds__(128) void mb_gate2c1_k(
    const float* __restrict__ cI, const float* __restrict__ m0,
    const float* __restrict__ wl, const float* __restrict__ Sb,
    const float* __restrict__ Tb, const float* __restrict__ Xb,
    float* __restrict__ h) {
  int blk = blockIdx.x;
  int coB = blk & 3, pb = (blk >> 2) & 7, b = blk >> 5;
  int tid = threadIdx.x, px = pb * 128 + tid;
  float acc[16];
#pragma unroll
  for (int c = 0; c < 16; ++c) acc[c] = 0.f;
  const float* ib1 = cI + (size_t)b * 65536 + px;
  const float* ib2 = m0 + (size_t)b * 65536 + px;
  for (int ci = 0; ci < 64; ++ci) {
    float v1 = ib1[ci * 1024], v2 = ib2[ci * 1024];
    const float* w1 = wl + (size_t)ci * 64 + coB * 16;
    const float* w2 = wl + (size_t)(64 + ci) * 64 + coB * 16;
#pragma unroll
    for (int c = 0; c < 16; ++c) {
      acc[c] = fmaf(w1[c], v1, acc[c]);
      acc[c] = fmaf(w2[c], v2, acc[c]);
    }
  }
#pragma unroll
  for (int c = 0; c < 16; ++c) {
    int co = coB * 16 + c;
    size_t o = (size_t)co * 1024 + px;
    float osum = Xb[(size_t)b * 262144 + 196608 + o] +
                 Tb[(size_t)b * 196608 + 131072 + o] +
                 Sb[(size_t)b * 262144 + 196608 + o];
    h[(size_t)b * 65536 + o] = sigf(osum) * tanhf(acc[c]);
  }
}

// final conv1 w_last + unpatchify. grid 128 x 64 thr
__global__ __launch_bounds__(64) void xgen_k(const float* __restrict__ h3,
                                             const float* __restrict__ wwl,
                                             float* __restrict__ xg,
                                             float* __restrict__ out, int t) {
  int blk = blockIdx.x;
  int pb = blk & 15, b = blk >> 4;
  int tid = threadIdx.x, px = pb * 64 + tid;
  float acc[16];
#pragma unroll
  for (int c = 0; c < 16; ++c) acc[c] = 0.f;
  const float* ib = h3 + (size_t)b * 65536 + px;
  for (int ci = 0; ci < 64; ++ci) {
    float v = ib[ci * 1024];
    const float* w = wwl + (size_t)ci * 16;
#pragma unroll
    for (int c = 0; c < 16; ++c) acc[c] = fmaf(w[c], v, acc[c]);
  }
  int y = px >> 5, x = px & 31;
#pragma unroll
  for (int c = 0; c < 16; ++c) {
    xg[(size_t)b * 16384 + (size_t)c * 1024 + px] = acc[c];
    if (t >= 9) {
      int py = c >> 2, pxs = c & 3;
      out[((size_t)b * 10 + (t - 9)) * 16384 + (y * 4 + py) * 128 + (x * 4 + pxs)] =
          acc[c];
    }
  }
}

// ---------------------------------------------------------------------------
extern "C" void kernel_launch(void* const* d_in, const int* in_sizes, int n_in,
                              void* d_out, int out_size, void* d_ws, size_t ws_size,
                              hipStream_t stream) {
  const float* frames0 = (const float*)d_in[0];
  const float* st_cx = (const float*)d_in[2];
  const float* st_ch = (const float*)d_in[3];
  const float* st_cm = (const float*)d_in[4];
  const float* st_co = (const float*)d_in[5];
  const float* st_cl = (const float*)d_in[6];
  const float* mb_t = (const float*)d_in[7];
  const float* mb_s = (const float*)d_in[8];
  const float* mb_x = (const float*)d_in[9];
  const float* mb_mh = (const float*)d_in[10];
  const float* mb_mx = (const float*)d_in[11];
  const float* mb_ctw = (const float*)d_in[12];
  const float* mb_ocw = (const float*)d_in[13];
  const float* mb_last = (const float*)d_in[14];
  const float* mn_ch = (const float*)d_in[15];
  const float* mn_cx = (const float*)d_in[16];
  const float* mn_ctw = (const float*)d_in[17];
  const float* mn_ocw = (const float*)d_in[18];
  const float* w_last = (const float*)d_in[19];
  float* out = (float*)d_out;

  float* ws = (float*)d_ws;
  size_t off = 0;
  auto A_ = [&](size_t n) { float* p = ws + off; off += n; return p; };
  float* hs[4]; for (int i = 0; i < 4; ++i) hs[i] = A_(S);
  float* cs[4]; for (int i = 0; i < 4; ++i) cs[i] = A_(S);
  float* memb = A_(S);
  float* dh[3]; for (int i = 0; i < 3; ++i) dh[i] = A_(S);
  float* dcb[3]; for (int i = 0; i < 3; ++i) dcb[i] = A_(S);
  float* ccb[3]; for (int i = 0; i < 3; ++i) ccb[i] = A_(S);
  float* diffb = A_(S);
  size_t zeroFloats = off;  // 19*S
  float* xgen = A_(131072);
  float* netb = A_(131072);
  float* R1 = A_(4 * S);    // STH / MNa / QX
  float* RB = A_(4 * S);    // MNb
  float* R2 = A_(3 * S);    // STM
  float* R2L[3]; for (int i = 0; i < 3; ++i) R2L[i] = A_(3 * S);  // T per layer
  float* R3 = A_(4 * S);    // X
  float* R5 = A_(4 * S);    // Sconv
  float* RML[3]; for (int i = 0; i < 3; ++i) RML[i] = A_(4 * S);  // MH per layer
  float* B64a = A_(S);      // STO partial (cs half)
  float* B64b = A_(S);      // STO partial (memb half)
  float* wtmbl[3]; for (int li = 0; li < 3; ++li) wtmbl[li] = A_(8192);
  float* wtcl = A_(8192);
  float* wtwl = A_(1024);
  us* warena = (us*)(ws + off);

  size_t wOff = 0;
  auto alloc = [&](int taps, int KS) {
    size_t o = wOff;
    wOff += (size_t)2 * taps * KS * 2048;
    return o;
  };
  size_t oSTH0n = alloc(25, 1), oSTH0h = alloc(25, 4);
  size_t oSTH1n = alloc(25, 1), oSTH1h = alloc(25, 4);
  size_t oSTM0n = alloc(25, 1), oSTM0m = alloc(25, 4);
  size_t oSTM1n = alloc(25, 1), oSTM1m = alloc(25, 4);
  size_t oSTOa = alloc(25, 4), oSTOb = alloc(25, 4);
  size_t oMNa0[3], oMNa1[3], oMNb0[3], oMNb1[3], oS0[3], oS1[3], oT0[3], oT1[3],
      oX0[3], oX1[3], oMH0[3], oMH1[3], oMX0[3], oMX1[3];
  for (int li = 0; li < 3; ++li) {
    oMNa0[li] = alloc(25, 4); oMNa1[li] = alloc(25, 4);
    oMNb0[li] = alloc(25, 4); oMNb1[li] = alloc(25, 4);
    oS0[li] = alloc(25, 4); oS1[li] = alloc(25, 4);
    oT0[li] = alloc(25, 4); oT1[li] = alloc(25, 4);
    oX0[li] = alloc(25, 4); oX1[li] = alloc(25, 4);
    oMH0[li] = alloc(25, 4); oMH1[li] = alloc(25, 4);
    oMX0[li] = alloc(25, 4); oMX1[li] = alloc(25, 4);
  }
  if (ws_size < off * sizeof(float) + wOff * sizeof(us)) return;

  hipMemsetAsync(ws, 0, zeroFloats * sizeof(float), stream);
  hipMemsetAsync(warena, 0, wOff * sizeof(us), stream);

  auto packL = [&](size_t dstOff, const float* src, int srcRow0, int nRows,
                   int dstRow0, int ciBase, int cinSrc, int taps, int KS) {
    int total = taps * KS * 4 * 64;
    pack_k<<<(total + 255) / 256, 256, 0, stream>>>(warena + dstOff, src, srcRow0,
                                                    nRows, dstRow0, ciBase, cinSrc,
                                                    taps, KS);
  };
  // st_cx rows: i(0) f(64) g(128) i'(192) f'(256) g'(320) o(384)
  packL(oSTH0n, st_cx, 0, 128, 0, 0, 16, 25, 1);
  packL(oSTH0h, st_ch, 0, 128, 0, 0, 64, 25, 4);
  packL(oSTH1n, st_cx, 128, 64, 0, 0, 16, 25, 1);
  packL(oSTH1n, st_cx, 384, 64, 64, 0, 16, 25, 1);
  packL(oSTH1h, st_ch, 128, 128, 0, 0, 64, 25, 4);
  packL(oSTM0n, st_cx, 192, 128, 0, 0, 16, 25, 1);
  packL(oSTM0m, st_cm, 0, 128, 0, 0, 64, 25, 4);
  packL(oSTM1n, st_cx, 320, 64, 0, 0, 16, 25, 1);
  packL(oSTM1m, st_cm, 128, 64, 0, 0, 64, 25, 4);
  packL(oSTOa, st_co, 0, 64, 0, 0, 128, 25, 4);
  packL(oSTOb, st_co, 0, 64, 0, 64, 128, 25, 4);
  for (int li = 0; li < 3; ++li) {
    const float* ch = mn_ch + (size_t)li * 409600;
    const float* cx = mn_cx + (size_t)li * 409600;
    const float* mbs = mb_s + (size_t)li * 409600;
    const float* mbt = mb_t + (size_t)li * 307200;
    const float* mbx = mb_x + (size_t)li * 409600;
    const float* mmh = mb_mh + (size_t)li * 409600;
    const float* mmx = mb_mx + (size_t)li * 409600;
    packL(oMNa0[li], ch, 0, 128, 0, 0, 64, 25, 4);
    packL(oMNa1[li], ch, 128, 128, 0, 0, 64, 25, 4);
    packL(oMNb0[li], cx, 0, 128, 0, 0, 64, 25, 4);
    packL(oMNb1[li], cx, 128, 128, 0, 0, 64, 25, 4);
    packL(oS0[li], mbs, 0, 128, 0, 0, 64, 25, 4);
    packL(oS1[li], mbs, 128, 128, 0, 0, 64, 25, 4);
    packL(oT0[li], mbt, 0, 128, 0, 0, 64, 25, 4);
    packL(oT1[li], mbt, 128, 64, 0, 0, 64, 25, 4);
    packL(oX0[li], mbx, 0, 128, 0, 0, 64, 25, 4);
    packL(oX1[li], mbx, 128, 128, 0, 0, 64, 25, 4);
    packL(oMH0[li], mmh, 0, 128, 0, 0, 64, 25, 4);
    packL(oMH1[li], mmh, 128, 128, 0, 0, 64, 25, 4);
    packL(oMX0[li], mmx, 0, 128, 0, 0, 64, 25, 4);
    packL(oMX1[li], mmx, 128, 128, 0, 0, 64, 25, 4);
    tr1_k<<<32, 256, 0, stream>>>(mb_last + (size_t)li * 8192, wtmbl[li], 128, 64);
  }
  tr1_k<<<32, 256, 0, stream>>>(st_cl, wtcl, 128, 64);
  tr1_k<<<4, 256, 0, stream>>>(w_last, wtwl, 64, 16);

  auto mkj = [&](const float* x0, size_t w0, int cin0, const float* x1, size_t w1,
                 int cin1, int taps, float* o, int outCo, int coBase, int coCnt) {
    Job j;
    j.x0 = x0; j.w0 = warena + w0; j.cin0 = cin0;
    j.x1 = x1; j.w1 = warena + w1; j.cin1 = cin1;
    j.taps = taps; j.out = o; j.outCo = outCo; j.coBase = coBase; j.coCnt = coCnt;
    return j;
  };
  auto launchB = [&](Batch& bt) {
    convmf6_k<4><<<bt.n * 64, 256, 0, stream>>>(bt);
  };
  auto launchB2 = [&](Batch& bt) {
    convmf6_k<2><<<bt.n * 128, 256, 0, stream>>>(bt);
  };

  for (int t = 0; t < 19; ++t) {
    const float* stIn = (t < 10) ? netb : xgen;
    if (t < 10) build_net_k<<<512, 256, 0, stream>>>(frames0, netb, t);
    {  // step-leading batch: STH+STM + all 3 layers' T+MH -> 16 jobs
      Batch P; P.n = 16;
      P.j[0] = mkj(stIn, oSTH0n, 16, hs[0], oSTH0h, 64, 25, R1, 256, 0, 128);
      P.j[1] = mkj(stIn, oSTH1n, 16, hs[0], oSTH1h, 64, 25, R1, 256, 128, 128);
      P.j[2] = mkj(stIn, oSTM0n, 16, memb, oSTM0m, 64, 25, R2, 192, 0, 128);
      P.j[3] = mkj(stIn, oSTM1n, 16, memb, oSTM1m, 64, 25, R2, 192, 128, 64);
      for (int li = 0; li < 3; ++li) {
        int i = li + 1;
        P.j[4 + li * 4 + 0] = mkj(hs[i], oT0[li], 64, nullptr, 0, 0, 25,
                                  R2L[li], 192, 0, 128);
        P.j[4 + li * 4 + 1] = mkj(hs[i], oT1[li], 64, nullptr, 0, 0, 25,
                                  R2L[li], 192, 128, 64);
        P.j[4 + li * 4 + 2] = mkj(cs[i], oMH0[li], 64, nullptr, 0, 0, 25,
                                  RML[li], 256, 0, 128);
        P.j[4 + li * 4 + 3] = mkj(cs[i], oMH1[li], 64, nullptr, 0, 0, 25,
                                  RML[li], 256, 128, 128);
      }
      launchB(P);
    }
    st_gate1_k<<<2048, 256, 0, stream>>>(R1, R2, cs[0], memb);
    {  // STO: 2 single-source jobs (partials), RPB=2 -> 256 blocks
      Batch P; P.n = 2;
      P.j[0] = mkj(cs[0], oSTOa, 64, nullptr, 0, 0, 25, B64a, 64, 0, 64);
      P.j[1] = mkj(memb, oSTOb, 64, nullptr, 0, 0, 25, B64b, 64, 0, 64);
      launchB2(P);
    }
    st_gate2c1_k<<<256, 128, 0, stream>>>(cs[0], memb, wtcl, R1, B64a, B64b, hs[0],
                                          diffb);

    for (int i = 1; i < 4; ++i) {
      int li = i - 1;
      const float* din = (i == 1) ? diffb : dh[i - 2];
      {  // A1: MNa + MNb + S + X -> 8 equal 64-ci jobs, one per XCD
        Batch P; int n = 0;
        if (t >= 1) {
          P.j[n++] = mkj(dh[li], oMNa0[li], 64, nullptr, 0, 0, 25, R1, 256, 0, 128);
          P.j[n++] = mkj(dh[li], oMNa1[li], 64, nullptr, 0, 0, 25, R1, 256, 128, 128);
          P.j[n++] = mkj(din, oMNb0[li], 64, nullptr, 0, 0, 25, RB, 256, 0, 128);
          P.j[n++] = mkj(din, oMNb1[li], 64, nullptr, 0, 0, 25, RB, 256, 128, 128);
        }
        P.j[n++] = mkj(memb, oS0[li], 64, nullptr, 0, 0, 25, R5, 256, 0, 128);
        P.j[n++] = mkj(memb, oS1[li], 64, nullptr, 0, 0, 25, R5, 256, 128, 128);
        P.j[n++] = mkj(hs[i - 1], oX0[li], 64, nullptr, 0, 0, 25, R3, 256, 0, 128);
        P.j[n++] = mkj(hs[i - 1], oX1[li], 64, nullptr, 0, 0, 25, R3, 256, 128, 128);
        P.n = n;
        launchB(P);
      }
      if (t >= 1)
        mimn_gate_k<<<2048, 256, 0, stream>>>(R1, RB, dh[li], dcb[li],
                                              mn_ctw + (size_t)li * 131072,
                                              mn_ocw + (size_t)li * 65536);
      {  // MX: RPB=2 -> 256 blocks (dh post-update; zeros at t=0 -> QX=0, OK)
        Batch P; P.n = 2;
        P.j[0] = mkj(dh[li], oMX0[li], 64, nullptr, 0, 0, 25, R1, 256, 0, 128);
        P.j[1] = mkj(dh[li], oMX1[li], 64, nullptr, 0, 0, 25, R1, 256, 128, 128);
        launchB2(P);
      }
      mb_gate1_k<<<2048, 256, 0, stream>>>(R5, R2L[li], R3, RML[li], R1, memb, cs[i],
                                           ccb[li], mb_ctw + (size_t)li * 131072,
                                           mb_ocw + (size_t)li * 65536);
      mb_gate2c1_k<<<256, 128, 0, stream>>>(cs[i], memb, wtmbl[li], R5, R2L[li], R3,
                                            hs[i]);
    }
    xgen_k<<<128, 64, 0, stream>>>(hs[3], wtwl, xgen, out, t);
  }
}